// Round 13
// baseline (704.471 us; speedup 1.0000x reference)
//
#include <hip/hip_runtime.h>
#include <cstdint>
#include <cstddef>

#define EPSF 1e-6f
#define BN_EPSF 1e-5f

constexpr int Bb = 4;
constexpr int Nn = 8192;
constexpr int KK = 20;
constexpr int SEG = 8;            // knn candidate segments
constexpr int SEGLEN = Nn / SEG;  // 1024
constexpr int BUF = 12;           // per-lane candidate buffer per query (LDS slots)

// ---------------- workspace layout (float elements) ----------------
constexpr size_t KNN0_OFF = 0;              // B*8*N*20 u32 = 5,242,880
constexpr size_t X1_OFF  = 0;               // B*21*3*N = 2,064,384
constexpr size_t X2_OFF  = 2064384;
constexpr size_t X3_OFF  = 4128768;         // B*42*3*N = 4,128,768 (ends 8,257,536)
constexpr size_t Z1_OFF  = 0;               // B*85*3*N = 8,355,840
constexpr size_t X4_OFF  = 8355840;         // 8,355,840
constexpr size_t IDX_OFF = 16711680;        // B*N*K ints = 655,360
constexpr size_t Z2_OFF  = 17367040;        // 4,128,768
constexpr size_t Z3_OFF  = 21495808;        // B*3*3*N = 294,912
constexpr size_t ACC_OFF = 21790720;        // 1024
constexpr size_t XM_OFF  = 21791744;        // 1020
constexpr size_t BF_OFF  = 21792764;        // 1020
constexpr size_t BD_OFF  = 21793784;        // 1020
constexpr size_t DEXT_OFF = 21795840;       // 8,355,840 (only if ws_size permits)
constexpr size_t EXT_NEED = (DEXT_OFF + 8355840) * 4;  // bytes

__device__ __forceinline__ float wave_sum(float v) {
#pragma unroll
  for (int off = 32; off; off >>= 1) v += __shfl_xor(v, off, 64);
  return v;
}
__device__ __forceinline__ float wave_max(float v) {
#pragma unroll
  for (int off = 32; off; off >>= 1) v = fmaxf(v, __shfl_xor(v, off, 64));
  return v;
}
__device__ __forceinline__ uint32_t umin32(uint32_t a, uint32_t b) { return a < b ? a : b; }
__device__ __forceinline__ uint32_t umax32(uint32_t a, uint32_t b) { return a < b ? b : a; }

// ---------------- zero accumulators ----------------
__global__ __launch_bounds__(1024) void zero_acc(float* __restrict__ a) {
  a[threadIdx.x] = 0.f;
}

// ---------------- KNN: 2 queries/thread, shared tile read, h-folded float screen ----------------
__global__ __launch_bounds__(256) void knn_kernel(const float* __restrict__ pts,
                                                  uint32_t* __restrict__ knnp) {
  __shared__ float4 tile[SEGLEN];          // 16 KB (xyz + 0.5|c|^2)
  __shared__ uint32_t buf0[BUF * 256];     // 12 KB
  __shared__ uint32_t buf1[BUF * 256];     // 12 KB  -> total 40 KB (same as R12)
  const int tid = threadIdx.x;
  const int n0 = blockIdx.x * 512 + tid;
  const int n1 = n0 + 256;
  const int b = blockIdx.y;
  const int s = blockIdx.z;
  const float* pb = pts + (size_t)b * Nn * 3;

  for (int i = tid; i < SEGLEN; i += 256) {
    const float* p = pb + (size_t)(s * SEGLEN + i) * 3;
    const float x = p[0], y = p[1], z = p[2];
    tile[i] = make_float4(x, y, z, 0.5f * (x * x + y * y + z * z));
  }
  const float q0x = pb[n0 * 3 + 0], q0y = pb[n0 * 3 + 1], q0z = pb[n0 * 3 + 2];
  const float q1x = pb[n1 * 3 + 0], q1y = pb[n1 * 3 + 1], q1z = pb[n1 * 3 + 2];
  const float h0 = 0.5f * (q0x * q0x + q0y * q0y + q0z * q0z);
  const float h1 = 0.5f * (q1x * q1x + q1y * q1y + q1z * q1z);
  const float nq0x = -q0x, nq0y = -q0y, nq0z = -q0z;
  const float nq1x = -q1x, nq1y = -q1y, nq1z = -q1z;
  __syncthreads();

  uint32_t keys0[KK], keys1[KK];
#pragma unroll
  for (int j = 0; j < KK; ++j) { keys0[j] = 0xFFFFFFFFu; keys1[j] = 0xFFFFFFFFu; }

  const int base = s * SEGLEN;

  // ---- warm-up: first 64 candidates, direct insert for both queries ----
#pragma unroll 2
  for (int j = 0; j < 64; ++j) {
    const float4 c = tile[j];
    const uint32_t tag = (uint32_t)(base + j);
    {
      float u = fmaf(nq0x, c.x, fmaf(nq0y, c.y, fmaf(nq0z, c.z, c.w + h0)));
      u = fmaxf(u, 0.f);
      uint32_t mx = (__float_as_uint(u) & 0xFFFFE000u) | tag;
#pragma unroll
      for (int q = 0; q < KK; ++q) {
        const uint32_t mn = umin32(keys0[q], mx);
        mx = umax32(keys0[q], mx);
        keys0[q] = mn;
      }
    }
    {
      float u = fmaf(nq1x, c.x, fmaf(nq1y, c.y, fmaf(nq1z, c.z, c.w + h1)));
      u = fmaxf(u, 0.f);
      uint32_t mx = (__float_as_uint(u) & 0xFFFFE000u) | tag;
#pragma unroll
      for (int q = 0; q < KK; ++q) {
        const uint32_t mn = umin32(keys1[q], mx);
        mx = umax32(keys1[q], mx);
        keys1[q] = mn;
      }
    }
  }

  uint32_t th0 = keys0[KK - 1], th1 = keys1[KK - 1];
  float tu0 = __uint_as_float((th0 & 0xFFFFE000u) + 0x2000u);
  float tu1 = __uint_as_float((th1 & 0xFFFFE000u) + 0x2000u);
  float thh0 = tu0 - h0 + 2.4e-7f * fabsf(tu0) + 1e-30f;
  float thh1 = tu1 - h1 + 2.4e-7f * fabsf(tu1) + 1e-30f;
  int cnt0 = 0, cnt1 = 0;

  for (int j0 = 64; j0 < SEGLEN; j0 += 4) {
#pragma unroll
    for (int u4 = 0; u4 < 4; ++u4) {
      const int j = j0 + u4;
      const float4 c = tile[j];
      const uint32_t tag = (uint32_t)(base + j);
      const float up0 = fmaf(nq0x, c.x, fmaf(nq0y, c.y, fmaf(nq0z, c.z, c.w)));
      if (up0 < thh0) {
        const float uc = fmaxf(up0 + h0, 0.f);
        buf0[cnt0 * 256 + tid] = (__float_as_uint(uc) & 0xFFFFE000u) | tag;
        ++cnt0;
      }
      const float up1 = fmaf(nq1x, c.x, fmaf(nq1y, c.y, fmaf(nq1z, c.z, c.w)));
      if (up1 < thh1) {
        const float uc = fmaxf(up1 + h1, 0.f);
        buf1[cnt1 * 256 + tid] = (__float_as_uint(uc) & 0xFFFFE000u) | tag;
        ++cnt1;
      }
    }
    if (__any((cnt0 > BUF - 4) || (cnt1 > BUF - 4))) {
#pragma unroll
      for (int i = 0; i < BUF; ++i) {
        uint32_t mx0 = (i < cnt0) ? buf0[i * 256 + tid] : 0xFFFFFFFFu;
        uint32_t mx1 = (i < cnt1) ? buf1[i * 256 + tid] : 0xFFFFFFFFu;
#pragma unroll
        for (int q = 0; q < KK; ++q) {
          const uint32_t mn0 = umin32(keys0[q], mx0);
          mx0 = umax32(keys0[q], mx0);
          keys0[q] = mn0;
          const uint32_t mn1 = umin32(keys1[q], mx1);
          mx1 = umax32(keys1[q], mx1);
          keys1[q] = mn1;
        }
      }
      cnt0 = 0; cnt1 = 0;
      th0 = keys0[KK - 1]; th1 = keys1[KK - 1];
      tu0 = __uint_as_float((th0 & 0xFFFFE000u) + 0x2000u);
      tu1 = __uint_as_float((th1 & 0xFFFFE000u) + 0x2000u);
      thh0 = tu0 - h0 + 2.4e-7f * fabsf(tu0) + 1e-30f;
      thh1 = tu1 - h1 + 2.4e-7f * fabsf(tu1) + 1e-30f;
    }
  }
  // ---- final flush ----
#pragma unroll
  for (int i = 0; i < BUF; ++i) {
    uint32_t mx0 = (i < cnt0) ? buf0[i * 256 + tid] : 0xFFFFFFFFu;
    uint32_t mx1 = (i < cnt1) ? buf1[i * 256 + tid] : 0xFFFFFFFFu;
#pragma unroll
    for (int q = 0; q < KK; ++q) {
      const uint32_t mn0 = umin32(keys0[q], mx0);
      mx0 = umax32(keys0[q], mx0);
      keys0[q] = mn0;
      const uint32_t mn1 = umin32(keys1[q], mx1);
      mx1 = umax32(keys1[q], mx1);
      keys1[q] = mn1;
    }
  }

  uint32_t* op0 = knnp + ((size_t)(b * SEG + s) * KK) * Nn + n0;
  uint32_t* op1 = knnp + ((size_t)(b * SEG + s) * KK) * Nn + n1;
#pragma unroll
  for (int j = 0; j < KK; ++j) { op0[(size_t)j * Nn] = keys0[j]; op1[(size_t)j * Nn] = keys1[j]; }
}

// ---------------- single-pass 8-way merge (keys unique -> deterministic) ----------------
__global__ __launch_bounds__(256) void merge8(const uint32_t* __restrict__ in,
                                              int* __restrict__ idx) {
  const int t = blockIdx.x * 256 + threadIdx.x;  // B*N threads
  const int n = t & (Nn - 1), b = t >> 13;
  const uint32_t* base = in + ((size_t)(b * SEG) * KK) * Nn + n;
  uint32_t h[SEG];
  int ii[SEG];
#pragma unroll
  for (int s = 0; s < SEG; ++s) {
    h[s] = base[(size_t)s * KK * Nn];
    ii[s] = 1;
  }
  int* op = idx + (size_t)t * KK;
#pragma unroll
  for (int m = 0; m < KK; ++m) {
    uint32_t k = h[0];
#pragma unroll
    for (int s = 1; s < SEG; ++s) k = umin32(k, h[s]);
    op[m] = (int)(k & 8191u);
#pragma unroll
    for (int s = 0; s < SEG; ++s) {
      if (h[s] == k) {
        h[s] = (ii[s] < KK) ? base[(size_t)s * KK * Nn + (size_t)ii[s] * Nn] : 0xFFFFFFFFu;
        ii[s]++;
      }
    }
  }
}

// ---------------- stage 1: feature-cross + LLR(21) ----------------
__global__ __launch_bounds__(256) void s1_stats(const float* __restrict__ pts,
                                                const int* __restrict__ idx,
                                                const float* __restrict__ wf,
                                                float* __restrict__ acc) {
  __shared__ float lacc[42];
  const int tid = threadIdx.x;
  for (int i = tid; i < 42; i += 256) lacc[i] = 0.f;
  __syncthreads();
  const int t = blockIdx.x * 256 + tid;  // 0..B*N*5-1
  const int site = t / 5;
  const int kq = (t % 5) * 4;
  const int n = site & (Nn - 1), b = site >> 13;
  const float* pb = pts + (size_t)b * Nn * 3;
  const float cx = pb[n * 3 + 0], cy = pb[n * 3 + 1], cz = pb[n * 3 + 2];
  float s1a[21], s2a[21];
#pragma unroll
  for (int o = 0; o < 21; ++o) { s1a[o] = 0.f; s2a[o] = 0.f; }
#pragma unroll
  for (int k = kq; k < kq + 4; ++k) {
    const int m = idx[(size_t)site * KK + k];
    const float ax = pb[m * 3 + 0], ay = pb[m * 3 + 1], az = pb[m * 3 + 2];
    const float e0x = ax - cx, e0y = ay - cy, e0z = az - cz;
    const float e2x = ay * cz - az * cy, e2y = az * cx - ax * cz, e2z = ax * cy - ay * cx;
#pragma unroll
    for (int o = 0; o < 21; ++o) {
      const float w0 = wf[o * 3 + 0], w1 = wf[o * 3 + 1], w2 = wf[o * 3 + 2];
      const float px = w0 * e0x + w1 * cx + w2 * e2x;
      const float py = w0 * e0y + w1 * cy + w2 * e2y;
      const float pz = w0 * e0z + w1 * cz + w2 * e2z;
      const float nrm = sqrtf(px * px + py * py + pz * pz) + EPSF;
      s1a[o] += nrm;
      s2a[o] += nrm * nrm;
    }
  }
#pragma unroll
  for (int o = 0; o < 21; ++o) {
    const float s1 = wave_sum(s1a[o]);
    const float s2 = wave_sum(s2a[o]);
    if ((tid & 63) == 0) { atomicAdd(&lacc[o], s1); atomicAdd(&lacc[21 + o], s2); }
  }
  __syncthreads();
  for (int i = tid; i < 42; i += 256) atomicAdd(&acc[i], lacc[i]);
}

// tile of 7 output channels per block (blockIdx.y)
__global__ __launch_bounds__(256) void s1_apply(const float* __restrict__ pts,
                                                const int* __restrict__ idx,
                                                const float* __restrict__ wf,
                                                const float* __restrict__ wd,
                                                const float* __restrict__ acc,
                                                float* __restrict__ x1) {
  const int t = blockIdx.x * 256 + threadIdx.x;  // site 0..B*N-1
  const int o0 = blockIdx.y * 7;
  const int n = t & (Nn - 1), b = t >> 13;
  const float* pb = pts + (size_t)b * Nn * 3;
  const float cx = pb[n * 3 + 0], cy = pb[n * 3 + 1], cz = pb[n * 3 + 2];
  const float inv_cnt = 1.f / (float)(Bb * Nn * KK);
  float meano[7], istdo[7];
#pragma unroll
  for (int j = 0; j < 7; ++j) {
    const float mn = acc[o0 + j] * inv_cnt;
    const float vr = acc[21 + o0 + j] * inv_cnt - mn * mn;
    meano[j] = mn;
    istdo[j] = rsqrtf(vr + BN_EPSF);
  }
  float accu[7][3];
#pragma unroll
  for (int j = 0; j < 7; ++j) { accu[j][0] = 0.f; accu[j][1] = 0.f; accu[j][2] = 0.f; }
  for (int k = 0; k < KK; ++k) {
    const int m = idx[(size_t)t * KK + k];
    const float ax = pb[m * 3 + 0], ay = pb[m * 3 + 1], az = pb[m * 3 + 2];
    const float e0x = ax - cx, e0y = ay - cy, e0z = az - cz;
    const float e2x = ay * cz - az * cy, e2y = az * cx - ax * cz, e2z = ax * cy - ay * cx;
#pragma unroll
    for (int j = 0; j < 7; ++j) {
      const int o = o0 + j;
      const float wf0 = wf[o * 3 + 0], wf1 = wf[o * 3 + 1], wf2 = wf[o * 3 + 2];
      const float px = wf0 * e0x + wf1 * cx + wf2 * e2x;
      const float py = wf0 * e0y + wf1 * cy + wf2 * e2y;
      const float pz = wf0 * e0z + wf1 * cz + wf2 * e2z;
      const float nrm = sqrtf(px * px + py * py + pz * pz) + EPSF;
      const float factor = (nrm - meano[j]) * istdo[j] / nrm;
      const float q0 = px * factor, q1 = py * factor, q2 = pz * factor;
      const float wd0 = wd[o * 3 + 0], wd1 = wd[o * 3 + 1], wd2 = wd[o * 3 + 2];
      const float dx = wd0 * e0x + wd1 * cx + wd2 * e2x;
      const float dy = wd0 * e0y + wd1 * cy + wd2 * e2y;
      const float dz = wd0 * e0z + wd1 * cz + wd2 * e2z;
      const float dot = q0 * dx + q1 * dy + q2 * dz;
      const float dsq = dx * dx + dy * dy + dz * dz;
      const float corr = (dot < 0.f) ? dot / (dsq + EPSF) : 0.f;
      accu[j][0] += q0 - corr * dx;
      accu[j][1] += q1 - corr * dy;
      accu[j][2] += q2 - corr * dz;
    }
  }
  const float sc = 1.f / (float)KK;
  float* ob = x1 + (size_t)b * 21 * 3 * Nn + n;
#pragma unroll
  for (int j = 0; j < 7; ++j) {
    const int o = o0 + j;
    ob[(o * 3 + 0) * Nn] = accu[j][0] * sc;
    ob[(o * 3 + 1) * Nn] = accu[j][1] * sc;
    ob[(o * 3 + 2) * Nn] = accu[j][2] * sc;
  }
}

// ---------------- VN layer, fully cached: stats computes p AND d ----------------
template <int CIN, int COUT, int OT, bool HAS_BIAS>
__global__ __launch_bounds__(256) void vn_stats_pd(const float* __restrict__ X,
                                                   const float* __restrict__ Wf,
                                                   const float* __restrict__ Wd, int ws,
                                                   const float* __restrict__ biasF,
                                                   const float* __restrict__ biasD,
                                                   float* __restrict__ acc,
                                                   float* __restrict__ P,
                                                   float* __restrict__ D) {
  __shared__ float lacc[2 * OT];
  const int tid = threadIdx.x;
  if (tid < 2 * OT) lacc[tid] = 0.f;
  __syncthreads();
  const int o0 = blockIdx.y * OT;
  const int t = blockIdx.x * 256 + tid;
  const int n = t & (Nn - 1), b = t >> 13;
  const float* xb = X + (size_t)b * CIN * 3 * Nn + n;
  float* pb = P + (size_t)b * COUT * 3 * Nn + n;
  float* db = D + (size_t)b * COUT * 3 * Nn + n;
  float p[OT][3], dv[OT][3];
#pragma unroll
  for (int j = 0; j < OT; ++j)
#pragma unroll
    for (int dd = 0; dd < 3; ++dd) {
      p[j][dd] = HAS_BIAS ? biasF[((size_t)b * COUT + o0 + j) * 3 + dd] : 0.f;
      dv[j][dd] = HAS_BIAS ? biasD[((size_t)b * COUT + o0 + j) * 3 + dd] : 0.f;
    }
  for (int c = 0; c < CIN; ++c) {
    const float x0 = xb[(c * 3 + 0) * Nn];
    const float x1v = xb[(c * 3 + 1) * Nn];
    const float x2v = xb[(c * 3 + 2) * Nn];
#pragma unroll
    for (int j = 0; j < OT; ++j) {
      const float wfv = Wf[(o0 + j) * ws + c];
      p[j][0] += wfv * x0; p[j][1] += wfv * x1v; p[j][2] += wfv * x2v;
      const float wdv = Wd[(o0 + j) * ws + c];
      dv[j][0] += wdv * x0; dv[j][1] += wdv * x1v; dv[j][2] += wdv * x2v;
    }
  }
#pragma unroll
  for (int j = 0; j < OT; ++j) {
    const int o = o0 + j;
    pb[(size_t)(o * 3 + 0) * Nn] = p[j][0];
    pb[(size_t)(o * 3 + 1) * Nn] = p[j][1];
    pb[(size_t)(o * 3 + 2) * Nn] = p[j][2];
    db[(size_t)(o * 3 + 0) * Nn] = dv[j][0];
    db[(size_t)(o * 3 + 1) * Nn] = dv[j][1];
    db[(size_t)(o * 3 + 2) * Nn] = dv[j][2];
  }
#pragma unroll
  for (int j = 0; j < OT; ++j) {
    const float nrm = sqrtf(p[j][0] * p[j][0] + p[j][1] * p[j][1] + p[j][2] * p[j][2]) + EPSF;
    const float s1 = wave_sum(nrm);
    const float s2 = wave_sum(nrm * nrm);
    if ((tid & 63) == 0) { atomicAdd(&lacc[j], s1); atomicAdd(&lacc[OT + j], s2); }
  }
  __syncthreads();
  if (tid < 2 * OT) {
    const int g = (tid < OT) ? (o0 + tid) : (COUT + o0 + (tid - OT));
    atomicAdd(&acc[g], lacc[tid]);
  }
}

__device__ __forceinline__ float llr_one(float p0, float p1, float p2,
                                         float d0, float d1, float d2,
                                         float mn, float istd,
                                         float& r0o, float& r1o, float& r2o) {
  const float nrm = sqrtf(p0 * p0 + p1 * p1 + p2 * p2) + EPSF;
  const float factor = (nrm - mn) * istd / nrm;
  float r0 = p0 * factor, r1 = p1 * factor, r2 = p2 * factor;
  const float dot = r0 * d0 + r1 * d1 + r2 * d2;
  const float dsq = d0 * d0 + d1 * d1 + d2 * d2;
  const float corr = (dot < 0.f) ? dot / (dsq + EPSF) : 0.f;
  r0o = r0 - corr * d0; r1o = r1 - corr * d1; r2o = r2 - corr * d2;
  return 0.f;
}

// elementwise BN + LLR over cached p,d (float4 across n); writes P in place.
template <int COUT>
__global__ __launch_bounds__(256) void vn_llr_ew4(const float* __restrict__ acc, float cntinv,
                                                  float* __restrict__ P,
                                                  const float* __restrict__ D) {
  const int t = blockIdx.x * 256 + threadIdx.x;  // (b, o, n4)
  const int n4 = t & (Nn / 4 - 1);
  const int r = t >> 11;
  const int o = r % COUT, b = r / COUT;
  float4* pp = (float4*)(P + ((size_t)(b * COUT + o) * 3) * Nn) + n4;
  const float4* dp = (const float4*)(D + ((size_t)(b * COUT + o) * 3) * Nn) + n4;
  const float4 p0 = pp[0], p1 = pp[Nn / 4], p2 = pp[2 * (Nn / 4)];
  const float4 d0 = dp[0], d1 = dp[Nn / 4], d2 = dp[2 * (Nn / 4)];
  const float mn = acc[o] * cntinv;
  const float vr = acc[COUT + o] * cntinv - mn * mn;
  const float istd = rsqrtf(vr + BN_EPSF);
  float4 r0, r1, r2;
  llr_one(p0.x, p1.x, p2.x, d0.x, d1.x, d2.x, mn, istd, r0.x, r1.x, r2.x);
  llr_one(p0.y, p1.y, p2.y, d0.y, d1.y, d2.y, mn, istd, r0.y, r1.y, r2.y);
  llr_one(p0.z, p1.z, p2.z, d0.z, d1.z, d2.z, mn, istd, r0.z, r1.z, r2.z);
  llr_one(p0.w, p1.w, p2.w, d0.w, d1.w, d2.w, mn, istd, r0.w, r1.w, r2.w);
  pp[0] = r0;
  pp[Nn / 4] = r1;
  pp[2 * (Nn / 4)] = r2;
}

// ---------------- p-only stats (layer 3) + fallback kernels ----------------
template <int CIN, int COUT, int OT, bool HAS_BIAS>
__global__ __launch_bounds__(256) void vn_stats_pc(const float* __restrict__ X,
                                                   const float* __restrict__ Wf, int ws,
                                                   const float* __restrict__ biasF,
                                                   float* __restrict__ acc,
                                                   float* __restrict__ P) {
  __shared__ float lacc[2 * OT];
  const int tid = threadIdx.x;
  if (tid < 2 * OT) lacc[tid] = 0.f;
  __syncthreads();
  const int o0 = blockIdx.y * OT;
  const int t = blockIdx.x * 256 + tid;
  const int n = t & (Nn - 1), b = t >> 13;
  const float* xb = X + (size_t)b * CIN * 3 * Nn + n;
  float* pb = P + (size_t)b * COUT * 3 * Nn + n;
  float p[OT][3];
#pragma unroll
  for (int j = 0; j < OT; ++j)
#pragma unroll
    for (int dd = 0; dd < 3; ++dd)
      p[j][dd] = HAS_BIAS ? biasF[((size_t)b * COUT + o0 + j) * 3 + dd] : 0.f;
  for (int c = 0; c < CIN; ++c) {
    const float x0 = xb[(c * 3 + 0) * Nn];
    const float x1v = xb[(c * 3 + 1) * Nn];
    const float x2v = xb[(c * 3 + 2) * Nn];
#pragma unroll
    for (int j = 0; j < OT; ++j) {
      const float wv = Wf[(o0 + j) * ws + c];
      p[j][0] += wv * x0; p[j][1] += wv * x1v; p[j][2] += wv * x2v;
    }
  }
#pragma unroll
  for (int j = 0; j < OT; ++j) {
    const int o = o0 + j;
    pb[(size_t)(o * 3 + 0) * Nn] = p[j][0];
    pb[(size_t)(o * 3 + 1) * Nn] = p[j][1];
    pb[(size_t)(o * 3 + 2) * Nn] = p[j][2];
  }
#pragma unroll
  for (int j = 0; j < OT; ++j) {
    const float nrm = sqrtf(p[j][0] * p[j][0] + p[j][1] * p[j][1] + p[j][2] * p[j][2]) + EPSF;
    const float s1 = wave_sum(nrm);
    const float s2 = wave_sum(nrm * nrm);
    if ((tid & 63) == 0) { atomicAdd(&lacc[j], s1); atomicAdd(&lacc[OT + j], s2); }
  }
  __syncthreads();
  if (tid < 2 * OT) {
    const int g = (tid < OT) ? (o0 + tid) : (COUT + o0 + (tid - OT));
    atomicAdd(&acc[g], lacc[tid]);
  }
}

template <int CIN, int COUT, int OT, bool HAS_BIAS>
__global__ __launch_bounds__(256) void vn_apply_pc(const float* __restrict__ X,
                                                   const float* __restrict__ Wd, int ws,
                                                   const float* __restrict__ biasD,
                                                   const float* __restrict__ acc, float cntinv,
                                                   float* __restrict__ P) {
  const int o0 = blockIdx.y * OT;
  const int t = blockIdx.x * 256 + threadIdx.x;
  const int n = t & (Nn - 1), b = t >> 13;
  const float* xb = X + (size_t)b * CIN * 3 * Nn + n;
  float* pb = P + (size_t)b * COUT * 3 * Nn + n;
  float dv[OT][3];
#pragma unroll
  for (int j = 0; j < OT; ++j)
#pragma unroll
    for (int dd = 0; dd < 3; ++dd)
      dv[j][dd] = HAS_BIAS ? biasD[((size_t)b * COUT + o0 + j) * 3 + dd] : 0.f;
  for (int c = 0; c < CIN; ++c) {
    const float x0 = xb[(c * 3 + 0) * Nn];
    const float x1v = xb[(c * 3 + 1) * Nn];
    const float x2v = xb[(c * 3 + 2) * Nn];
#pragma unroll
    for (int j = 0; j < OT; ++j) {
      const float wdv = Wd[(o0 + j) * ws + c];
      dv[j][0] += wdv * x0; dv[j][1] += wdv * x1v; dv[j][2] += wdv * x2v;
    }
  }
#pragma unroll
  for (int j = 0; j < OT; ++j) {
    const int o = o0 + j;
    const float p0 = pb[(size_t)(o * 3 + 0) * Nn];
    const float p1 = pb[(size_t)(o * 3 + 1) * Nn];
    const float p2 = pb[(size_t)(o * 3 + 2) * Nn];
    const float nrm = sqrtf(p0 * p0 + p1 * p1 + p2 * p2) + EPSF;
    const float mn = acc[o] * cntinv;
    const float vr = acc[COUT + o] * cntinv - mn * mn;
    const float factor = (nrm - mn) * rsqrtf(vr + BN_EPSF) / nrm;
    float r0 = p0 * factor, r1 = p1 * factor, r2 = p2 * factor;
    const float dot = r0 * dv[j][0] + r1 * dv[j][1] + r2 * dv[j][2];
    const float dsq = dv[j][0] * dv[j][0] + dv[j][1] * dv[j][1] + dv[j][2] * dv[j][2];
    const float corr = (dot < 0.f) ? dot / (dsq + EPSF) : 0.f;
    r0 -= corr * dv[j][0]; r1 -= corr * dv[j][1]; r2 -= corr * dv[j][2];
    pb[(size_t)(o * 3 + 0) * Nn] = r0;
    pb[(size_t)(o * 3 + 1) * Nn] = r1;
    pb[(size_t)(o * 3 + 2) * Nn] = r2;
  }
}

// non-LLR layer: elementwise BN over cached p (float4 across n), in place.
template <int COUT>
__global__ __launch_bounds__(256) void vn_bn4(const float* __restrict__ acc, float cntinv,
                                              float* __restrict__ P) {
  const int t = blockIdx.x * 256 + threadIdx.x;  // (b, o, n4)
  const int n4 = t & (Nn / 4 - 1);
  const int r = t >> 11;
  const int o = r % COUT, b = r / COUT;
  float4* pp = (float4*)(P + ((size_t)(b * COUT + o) * 3) * Nn) + n4;
  const float4 p0 = pp[0], p1 = pp[Nn / 4], p2 = pp[2 * (Nn / 4)];
  const float mn = acc[o] * cntinv;
  const float vr = acc[COUT + o] * cntinv - mn * mn;
  const float istd = rsqrtf(vr + BN_EPSF);
  float4 r0, r1, r2;
#define BN_ONE(f) {                                                        \
    const float nrm = sqrtf(p0.f * p0.f + p1.f * p1.f + p2.f * p2.f) + EPSF; \
    const float factor = (nrm - mn) * istd / nrm;                          \
    r0.f = p0.f * factor; r1.f = p1.f * factor; r2.f = p2.f * factor; }
  BN_ONE(x) BN_ONE(y) BN_ONE(z) BN_ONE(w)
#undef BN_ONE
  pp[0] = r0;
  pp[Nn / 4] = r1;
  pp[2 * (Nn / 4)] = r2;
}

// ---------------- stage 5: mean over N, bias precompute, small outputs ----------------
__global__ __launch_bounds__(256) void s5_mean(const float* __restrict__ x4,
                                               float* __restrict__ xm,
                                               float* __restrict__ out) {
  const int row = blockIdx.x;  // 0..1019 = b*255 + c*3 + dd
  const int b = row / 255, rcd = row % 255;
  const float* src = x4 + (size_t)b * 255 * Nn + (size_t)rcd * Nn;
  float s = 0.f;
  for (int n = threadIdx.x; n < Nn; n += 256) s += src[n];
  s = wave_sum(s);
  __shared__ float wsum[4];
  if ((threadIdx.x & 63) == 0) wsum[threadIdx.x >> 6] = s;
  __syncthreads();
  if (threadIdx.x == 0) {
    const float mv = (wsum[0] + wsum[1] + wsum[2] + wsum[3]) * (1.f / (float)Nn);
    xm[row] = mv;
    out[2040 + row] = mv;  // x_mean_out
  }
}

__global__ __launch_bounds__(256) void s5_bias(const float* __restrict__ xm,
                                               const float* __restrict__ ws1f,
                                               const float* __restrict__ ws1d,
                                               float* __restrict__ biasF,
                                               float* __restrict__ biasD,
                                               float* __restrict__ out) {
  const int t = blockIdx.x * 256 + threadIdx.x;
  if (t < 1020) {
    const int b = t / 255, r = t % 255, o = r / 3, dd = r % 3;
    float sf = 0.f, sd = 0.f;
    for (int c = 0; c < 85; ++c) {
      const float xv = xm[(b * 85 + c) * 3 + dd];
      sf += ws1f[o * 170 + 85 + c] * xv;
      sd += ws1d[o * 170 + 85 + c] * xv;
    }
    biasF[t] = sf;
    biasD[t] = sd;
  }
  if (t < 340) {
    const int b = t / 85, c = t % 85;
    out[3060 + t] = (xm[(b * 85 + c) * 3 + 0] + xm[(b * 85 + c) * 3 + 1] +
                     xm[(b * 85 + c) * 3 + 2]) * (1.f / 3.f);  // center_loc
  }
}

// ---------------- stage 8: z3 = wlin · z2 ----------------
__global__ __launch_bounds__(256) void s8_z3(const float* __restrict__ z2,
                                             const float* __restrict__ wlin,
                                             float* __restrict__ z3) {
  const int t = blockIdx.x * 256 + threadIdx.x;
  const int n = t & (Nn - 1), b = t >> 13;
  const float* zb = z2 + (size_t)b * 42 * 3 * Nn + n;
  float accv[3][3];
#pragma unroll
  for (int o = 0; o < 3; ++o)
#pragma unroll
    for (int dd = 0; dd < 3; ++dd) accv[o][dd] = 0.f;
  for (int c = 0; c < 42; ++c) {
    const float x0 = zb[(c * 3 + 0) * Nn];
    const float x1v = zb[(c * 3 + 1) * Nn];
    const float x2v = zb[(c * 3 + 2) * Nn];
#pragma unroll
    for (int o = 0; o < 3; ++o) {
      const float wv = wlin[o * 42 + c];
      accv[o][0] += wv * x0; accv[o][1] += wv * x1v; accv[o][2] += wv * x2v;
    }
  }
  float* ob = z3 + (size_t)b * 9 * Nn + n;
#pragma unroll
  for (int o = 0; o < 3; ++o)
#pragma unroll
    for (int dd = 0; dd < 3; ++dd) ob[(o * 3 + dd) * Nn] = accv[o][dd];
}

// ---------------- stage 9: x_std + max over N ----------------
__global__ __launch_bounds__(256) void s9_max(const float* __restrict__ x4,
                                              const float* __restrict__ xm,
                                              const float* __restrict__ z3,
                                              float* __restrict__ out) {
  const int tile = blockIdx.x;  // 0..33
  const int b = blockIdx.y;
  const int i0 = tile * 5;
  const bool upper = (i0 >= 85);
  float mx[15];
#pragma unroll
  for (int r = 0; r < 15; ++r) mx[r] = -3.402823466e38f;
  float xmr[5][3];
  if (upper) {
#pragma unroll
    for (int ii = 0; ii < 5; ++ii)
#pragma unroll
      for (int j = 0; j < 3; ++j) xmr[ii][j] = xm[(b * 85 + (i0 - 85 + ii)) * 3 + j];
  }
  const float* zb = z3 + (size_t)b * 9 * Nn;
  const float* xb = x4 + (size_t)b * 255 * Nn;
  for (int n = threadIdx.x; n < Nn; n += 256) {
    float zk[3][3];
#pragma unroll
    for (int k = 0; k < 3; ++k)
#pragma unroll
      for (int j = 0; j < 3; ++j) zk[k][j] = zb[(k * 3 + j) * Nn + n];
#pragma unroll
    for (int ii = 0; ii < 5; ++ii) {
      float xj0, xj1, xj2;
      if (upper) {
        xj0 = xmr[ii][0]; xj1 = xmr[ii][1]; xj2 = xmr[ii][2];
      } else {
        xj0 = xb[((i0 + ii) * 3 + 0) * Nn + n];
        xj1 = xb[((i0 + ii) * 3 + 1) * Nn + n];
        xj2 = xb[((i0 + ii) * 3 + 2) * Nn + n];
      }
#pragma unroll
      for (int k = 0; k < 3; ++k) {
        const float v = xj0 * zk[k][0] + xj1 * zk[k][1] + xj2 * zk[k][2];
        mx[ii * 3 + k] = fmaxf(mx[ii * 3 + k], v);
      }
    }
  }
  __shared__ float red[4 * 15];
#pragma unroll
  for (int r = 0; r < 15; ++r) {
    const float v = wave_max(mx[r]);
    if ((threadIdx.x & 63) == 0) red[(threadIdx.x >> 6) * 15 + r] = v;
  }
  __syncthreads();
  if (threadIdx.x < 15) {
    const float v = fmaxf(fmaxf(red[threadIdx.x], red[15 + threadIdx.x]),
                          fmaxf(red[30 + threadIdx.x], red[45 + threadIdx.x]));
    out[b * 510 + i0 * 3 + threadIdx.x] = v;
  }
}

// ---------------- launch ----------------
extern "C" void kernel_launch(void* const* d_in, const int* in_sizes, int n_in,
                              void* d_out, int out_size, void* d_ws, size_t ws_size,
                              hipStream_t stream) {
  const float* pts   = (const float*)d_in[0];
  const float* wposf = (const float*)d_in[1];
  const float* wposd = (const float*)d_in[2];
  const float* w1f   = (const float*)d_in[3];
  const float* w1d   = (const float*)d_in[4];
  const float* w2f   = (const float*)d_in[5];
  const float* w2d   = (const float*)d_in[6];
  const float* w3    = (const float*)d_in[7];
  const float* ws1f  = (const float*)d_in[8];
  const float* ws1d  = (const float*)d_in[9];
  const float* ws2f  = (const float*)d_in[10];
  const float* ws2d  = (const float*)d_in[11];
  const float* wlin  = (const float*)d_in[12];
  float* out = (float*)d_out;
  float* wsf = (float*)d_ws;

  uint32_t* knnp0 = (uint32_t*)(wsf + KNN0_OFF);
  float* x1 = wsf + X1_OFF;
  float* x2 = wsf + X2_OFF;
  float* x3 = wsf + X3_OFF;
  float* z1 = wsf + Z1_OFF;
  float* x4 = wsf + X4_OFF;
  int* idx  = (int*)(wsf + IDX_OFF);
  float* z2 = wsf + Z2_OFF;
  float* z3 = wsf + Z3_OFF;
  float* acc = wsf + ACC_OFF;
  float* xm = wsf + XM_OFF;
  float* biasF = wsf + BF_OFF;
  float* biasD = wsf + BD_OFF;
  float* d1 = wsf + X3_OFF;   // dead region before x3 written
  float* d2 = wsf + X4_OFF;   // dead region before x4 written
  float* dext = wsf + DEXT_OFF;
  const bool ext = ws_size >= EXT_NEED;

  const float inv_sites = 1.f / (float)(Bb * Nn);

  zero_acc<<<1, 1024, 0, stream>>>(acc);
  knn_kernel<<<dim3(Nn / 512, Bb, SEG), 256, 0, stream>>>(pts, knnp0);
  merge8<<<Bb * Nn / 256, 256, 0, stream>>>(knnp0, idx);

  s1_stats<<<Bb * Nn * 5 / 256, 256, 0, stream>>>(pts, idx, wposf, acc + 0);
  s1_apply<<<dim3(Bb * Nn / 256, 3), 256, 0, stream>>>(pts, idx, wposf, wposd, acc + 0, x1);

  // layer <21,21> LLR: fused p+d stats, elementwise LLR (float4)
  vn_stats_pd<21, 21, 7, false><<<dim3(Bb * Nn / 256, 3), 256, 0, stream>>>(
      x1, w1f, w1d, 21, nullptr, nullptr, acc + 64, x2, d1);
  vn_llr_ew4<21><<<Bb * 21 * Nn / 4 / 256, 256, 0, stream>>>(acc + 64, inv_sites, x2, d1);

  // layer <21,42> LLR
  vn_stats_pd<21, 42, 7, false><<<dim3(Bb * Nn / 256, 6), 256, 0, stream>>>(
      x2, w2f, w2d, 42, nullptr, nullptr, acc + 128, x3, d2);
  vn_llr_ew4<42><<<Bb * 42 * Nn / 4 / 256, 256, 0, stream>>>(acc + 128, inv_sites, x3, d2);

  // layer <42,85> no LLR: p-only stats (OT=5, high occupancy) + elementwise BN (float4)
  vn_stats_pc<42, 85, 5, false><<<dim3(Bb * Nn / 256, 17), 256, 0, stream>>>(
      x3, w3, 42, nullptr, acc + 256, x4);
  vn_bn4<85><<<Bb * 85 * Nn / 4 / 256, 256, 0, stream>>>(acc + 256, inv_sites, x4);

  s5_mean<<<Bb * 255, 256, 0, stream>>>(x4, xm, out);
  s5_bias<<<4, 256, 0, stream>>>(xm, ws1f, ws1d, biasF, biasD, out);

  if (ext) {
    vn_stats_pd<85, 85, 5, true><<<dim3(Bb * Nn / 256, 17), 256, 0, stream>>>(
        x4, ws1f, ws1d, 170, biasF, biasD, acc + 512, z1, dext);
    vn_llr_ew4<85><<<Bb * 85 * Nn / 4 / 256, 256, 0, stream>>>(acc + 512, inv_sites, z1, dext);
    vn_stats_pd<85, 42, 7, false><<<dim3(Bb * Nn / 256, 6), 256, 0, stream>>>(
        z1, ws2f, ws2d, 85, nullptr, nullptr, acc + 768, z2, dext);
    vn_llr_ew4<42><<<Bb * 42 * Nn / 4 / 256, 256, 0, stream>>>(acc + 768, inv_sites, z2, dext);
  } else {
    vn_stats_pc<85, 85, 17, true><<<dim3(Bb * Nn / 256, 5), 256, 0, stream>>>(
        x4, ws1f, 170, biasF, acc + 512, z1);
    vn_apply_pc<85, 85, 17, true><<<dim3(Bb * Nn / 256, 5), 256, 0, stream>>>(
        x4, ws1d, 170, biasD, acc + 512, inv_sites, z1);
    vn_stats_pc<85, 42, 14, false><<<dim3(Bb * Nn / 256, 3), 256, 0, stream>>>(
        z1, ws2f, 85, nullptr, acc + 768, z2);
    vn_apply_pc<85, 42, 14, false><<<dim3(Bb * Nn / 256, 3), 256, 0, stream>>>(
        z1, ws2d, 85, nullptr, acc + 768, inv_sites, z2);
  }

  s8_z3<<<Bb * Nn / 256, 256, 0, stream>>>(z2, wlin, z3);
  s9_max<<<dim3(34, Bb), 256, 0, stream>>>(x4, xm, z3, out);
}

// Round 14
// 663.840 us; speedup vs baseline: 1.0612x; 1.0612x over previous
//
#include <hip/hip_runtime.h>
#include <cstdint>
#include <cstddef>

#define EPSF 1e-6f
#define BN_EPSF 1e-5f

constexpr int Bb = 4;
constexpr int Nn = 8192;
constexpr int KK = 20;
constexpr int SEG = 8;            // knn candidate segments
constexpr int SEGLEN = Nn / SEG;  // 1024
constexpr int BUF = 24;           // per-lane candidate buffer (LDS slots)

// ---------------- workspace layout (float elements) ----------------
constexpr size_t KNN0_OFF = 0;              // B*8*N*20 u32 = 5,242,880
constexpr size_t X1_OFF  = 0;               // B*21*3*N = 2,064,384
constexpr size_t X2_OFF  = 2064384;
constexpr size_t X3_OFF  = 4128768;         // B*42*3*N = 4,128,768 (ends 8,257,536)
constexpr size_t Z1_OFF  = 0;               // B*85*3*N = 8,355,840
constexpr size_t X4_OFF  = 8355840;         // 8,355,840
constexpr size_t IDX_OFF = 16711680;        // B*N*K ints = 655,360
constexpr size_t Z2_OFF  = 17367040;        // 4,128,768
constexpr size_t Z3_OFF  = 21495808;        // B*3*3*N = 294,912
constexpr size_t ACC_OFF = 21790720;        // 1024
constexpr size_t XM_OFF  = 21791744;        // 1020
constexpr size_t BF_OFF  = 21792764;        // 1020
constexpr size_t BD_OFF  = 21793784;        // 1020
constexpr size_t DEXT_OFF = 21795840;       // 8,355,840 (only if ws_size permits)
constexpr size_t EXT_NEED = (DEXT_OFF + 8355840) * 4;  // bytes

__device__ __forceinline__ float wave_sum(float v) {
#pragma unroll
  for (int off = 32; off; off >>= 1) v += __shfl_xor(v, off, 64);
  return v;
}
__device__ __forceinline__ float wave_max(float v) {
#pragma unroll
  for (int off = 32; off; off >>= 1) v = fmaxf(v, __shfl_xor(v, off, 64));
  return v;
}
__device__ __forceinline__ uint32_t umin32(uint32_t a, uint32_t b) { return a < b ? a : b; }
__device__ __forceinline__ uint32_t umax32(uint32_t a, uint32_t b) { return a < b ? b : a; }

// ---------------- zero accumulators ----------------
__global__ __launch_bounds__(1024) void zero_acc(float* __restrict__ a) {
  a[threadIdx.x] = 0.f;
}

// ---------------- KNN: buffered top-20, h-folded float screen (R12, proven 186us) ----------------
__global__ __launch_bounds__(256) void knn_kernel(const float* __restrict__ pts,
                                                  uint32_t* __restrict__ knnp) {
  __shared__ float4 tile[SEGLEN];          // 16 KB (xyz + 0.5|c|^2)
  __shared__ uint32_t buf[BUF * 256];      // 24 KB
  const int tid = threadIdx.x;
  const int n = blockIdx.x * 256 + tid;
  const int b = blockIdx.y;
  const int s = blockIdx.z;
  const float* pb = pts + (size_t)b * Nn * 3;

  for (int i = tid; i < SEGLEN; i += 256) {
    const float* p = pb + (size_t)(s * SEGLEN + i) * 3;
    const float x = p[0], y = p[1], z = p[2];
    tile[i] = make_float4(x, y, z, 0.5f * (x * x + y * y + z * z));
  }
  const float qx = pb[n * 3 + 0], qy = pb[n * 3 + 1], qz = pb[n * 3 + 2];
  const float nqx = -qx, nqy = -qy, nqz = -qz;
  const float h = 0.5f * (qx * qx + qy * qy + qz * qz);
  __syncthreads();

  uint32_t keys[KK];
#pragma unroll
  for (int j = 0; j < KK; ++j) keys[j] = 0xFFFFFFFFu;

  const int base = s * SEGLEN;

#pragma unroll 4
  for (int j = 0; j < 64; ++j) {
    const float4 c = tile[j];
    float u = fmaf(nqx, c.x, fmaf(nqy, c.y, fmaf(nqz, c.z, c.w + h)));
    u = fmaxf(u, 0.f);
    uint32_t mx = (__float_as_uint(u) & 0xFFFFE000u) | (uint32_t)(base + j);
#pragma unroll
    for (int q = 0; q < KK; ++q) {
      const uint32_t mn = umin32(keys[q], mx);
      mx = umax32(keys[q], mx);
      keys[q] = mn;
    }
  }

  uint32_t thresh = keys[KK - 1];
  float thresh_up = __uint_as_float((thresh & 0xFFFFE000u) + 0x2000u);
  float th_h = thresh_up - h + 2.4e-7f * fabsf(thresh_up) + 1e-30f;
  int cnt = 0;

  for (int j0 = 64; j0 < SEGLEN; j0 += 4) {
#pragma unroll
    for (int u4 = 0; u4 < 4; ++u4) {
      const int j = j0 + u4;
      const float4 c = tile[j];
      const float up = fmaf(nqx, c.x, fmaf(nqy, c.y, fmaf(nqz, c.z, c.w)));
      if (up < th_h) {
        const float uc = fmaxf(up + h, 0.f);
        buf[cnt * 256 + tid] = (__float_as_uint(uc) & 0xFFFFE000u) | (uint32_t)(base + j);
        ++cnt;
      }
    }
    if (__any(cnt > BUF - 4)) {
#pragma unroll
      for (int i = 0; i < BUF; ++i) {
        uint32_t mx = (i < cnt) ? buf[i * 256 + tid] : 0xFFFFFFFFu;
#pragma unroll
        for (int q = 0; q < KK; ++q) {
          const uint32_t mn = umin32(keys[q], mx);
          mx = umax32(keys[q], mx);
          keys[q] = mn;
        }
      }
      cnt = 0;
      thresh = keys[KK - 1];
      thresh_up = __uint_as_float((thresh & 0xFFFFE000u) + 0x2000u);
      th_h = thresh_up - h + 2.4e-7f * fabsf(thresh_up) + 1e-30f;
    }
  }
#pragma unroll
  for (int i = 0; i < BUF; ++i) {
    uint32_t mx = (i < cnt) ? buf[i * 256 + tid] : 0xFFFFFFFFu;
#pragma unroll
    for (int q = 0; q < KK; ++q) {
      const uint32_t mn = umin32(keys[q], mx);
      mx = umax32(keys[q], mx);
      keys[q] = mn;
    }
  }

  uint32_t* op = knnp + ((size_t)(b * SEG + s) * KK) * Nn + n;
#pragma unroll
  for (int j = 0; j < KK; ++j) op[(size_t)j * Nn] = keys[j];
}

// ---------------- single-pass 8-way merge (keys unique -> deterministic) ----------------
__global__ __launch_bounds__(256) void merge8(const uint32_t* __restrict__ in,
                                              int* __restrict__ idx) {
  const int t = blockIdx.x * 256 + threadIdx.x;  // B*N threads
  const int n = t & (Nn - 1), b = t >> 13;
  const uint32_t* base = in + ((size_t)(b * SEG) * KK) * Nn + n;
  uint32_t h[SEG];
  int ii[SEG];
#pragma unroll
  for (int s = 0; s < SEG; ++s) {
    h[s] = base[(size_t)s * KK * Nn];
    ii[s] = 1;
  }
  int* op = idx + (size_t)t * KK;
#pragma unroll
  for (int m = 0; m < KK; ++m) {
    uint32_t k = h[0];
#pragma unroll
    for (int s = 1; s < SEG; ++s) k = umin32(k, h[s]);
    op[m] = (int)(k & 8191u);
#pragma unroll
    for (int s = 0; s < SEG; ++s) {
      if (h[s] == k) {
        h[s] = (ii[s] < KK) ? base[(size_t)s * KK * Nn + (size_t)ii[s] * Nn] : 0xFFFFFFFFu;
        ii[s]++;
      }
    }
  }
}

// ---------------- stage 1: feature-cross + LLR(21) ----------------
__global__ __launch_bounds__(256) void s1_stats(const float* __restrict__ pts,
                                                const int* __restrict__ idx,
                                                const float* __restrict__ wf,
                                                float* __restrict__ acc) {
  __shared__ float lacc[42];
  const int tid = threadIdx.x;
  for (int i = tid; i < 42; i += 256) lacc[i] = 0.f;
  __syncthreads();
  const int t = blockIdx.x * 256 + tid;  // 0..B*N*5-1
  const int site = t / 5;
  const int kq = (t % 5) * 4;
  const int n = site & (Nn - 1), b = site >> 13;
  const float* pb = pts + (size_t)b * Nn * 3;
  const float cx = pb[n * 3 + 0], cy = pb[n * 3 + 1], cz = pb[n * 3 + 2];
  float s1a[21], s2a[21];
#pragma unroll
  for (int o = 0; o < 21; ++o) { s1a[o] = 0.f; s2a[o] = 0.f; }
#pragma unroll
  for (int k = kq; k < kq + 4; ++k) {
    const int m = idx[(size_t)site * KK + k];
    const float ax = pb[m * 3 + 0], ay = pb[m * 3 + 1], az = pb[m * 3 + 2];
    const float e0x = ax - cx, e0y = ay - cy, e0z = az - cz;
    const float e2x = ay * cz - az * cy, e2y = az * cx - ax * cz, e2z = ax * cy - ay * cx;
#pragma unroll
    for (int o = 0; o < 21; ++o) {
      const float w0 = wf[o * 3 + 0], w1 = wf[o * 3 + 1], w2 = wf[o * 3 + 2];
      const float px = w0 * e0x + w1 * cx + w2 * e2x;
      const float py = w0 * e0y + w1 * cy + w2 * e2y;
      const float pz = w0 * e0z + w1 * cz + w2 * e2z;
      const float nrm = sqrtf(px * px + py * py + pz * pz) + EPSF;
      s1a[o] += nrm;
      s2a[o] += nrm * nrm;
    }
  }
#pragma unroll
  for (int o = 0; o < 21; ++o) {
    const float s1 = wave_sum(s1a[o]);
    const float s2 = wave_sum(s2a[o]);
    if ((tid & 63) == 0) { atomicAdd(&lacc[o], s1); atomicAdd(&lacc[21 + o], s2); }
  }
  __syncthreads();
  for (int i = tid; i < 42; i += 256) atomicAdd(&acc[i], lacc[i]);
}

// tile of 7 output channels per block (blockIdx.y)
__global__ __launch_bounds__(256) void s1_apply(const float* __restrict__ pts,
                                                const int* __restrict__ idx,
                                                const float* __restrict__ wf,
                                                const float* __restrict__ wd,
                                                const float* __restrict__ acc,
                                                float* __restrict__ x1) {
  const int t = blockIdx.x * 256 + threadIdx.x;  // site 0..B*N-1
  const int o0 = blockIdx.y * 7;
  const int n = t & (Nn - 1), b = t >> 13;
  const float* pb = pts + (size_t)b * Nn * 3;
  const float cx = pb[n * 3 + 0], cy = pb[n * 3 + 1], cz = pb[n * 3 + 2];
  const float inv_cnt = 1.f / (float)(Bb * Nn * KK);
  float meano[7], istdo[7];
#pragma unroll
  for (int j = 0; j < 7; ++j) {
    const float mn = acc[o0 + j] * inv_cnt;
    const float vr = acc[21 + o0 + j] * inv_cnt - mn * mn;
    meano[j] = mn;
    istdo[j] = rsqrtf(vr + BN_EPSF);
  }
  float accu[7][3];
#pragma unroll
  for (int j = 0; j < 7; ++j) { accu[j][0] = 0.f; accu[j][1] = 0.f; accu[j][2] = 0.f; }
  for (int k = 0; k < KK; ++k) {
    const int m = idx[(size_t)t * KK + k];
    const float ax = pb[m * 3 + 0], ay = pb[m * 3 + 1], az = pb[m * 3 + 2];
    const float e0x = ax - cx, e0y = ay - cy, e0z = az - cz;
    const float e2x = ay * cz - az * cy, e2y = az * cx - ax * cz, e2z = ax * cy - ay * cx;
#pragma unroll
    for (int j = 0; j < 7; ++j) {
      const int o = o0 + j;
      const float wf0 = wf[o * 3 + 0], wf1 = wf[o * 3 + 1], wf2 = wf[o * 3 + 2];
      const float px = wf0 * e0x + wf1 * cx + wf2 * e2x;
      const float py = wf0 * e0y + wf1 * cy + wf2 * e2y;
      const float pz = wf0 * e0z + wf1 * cz + wf2 * e2z;
      const float nrm = sqrtf(px * px + py * py + pz * pz) + EPSF;
      const float factor = (nrm - meano[j]) * istdo[j] / nrm;
      const float q0 = px * factor, q1 = py * factor, q2 = pz * factor;
      const float wd0 = wd[o * 3 + 0], wd1 = wd[o * 3 + 1], wd2 = wd[o * 3 + 2];
      const float dx = wd0 * e0x + wd1 * cx + wd2 * e2x;
      const float dy = wd0 * e0y + wd1 * cy + wd2 * e2y;
      const float dz = wd0 * e0z + wd1 * cz + wd2 * e2z;
      const float dot = q0 * dx + q1 * dy + q2 * dz;
      const float dsq = dx * dx + dy * dy + dz * dz;
      const float corr = (dot < 0.f) ? dot / (dsq + EPSF) : 0.f;
      accu[j][0] += q0 - corr * dx;
      accu[j][1] += q1 - corr * dy;
      accu[j][2] += q2 - corr * dz;
    }
  }
  const float sc = 1.f / (float)KK;
  float* ob = x1 + (size_t)b * 21 * 3 * Nn + n;
#pragma unroll
  for (int j = 0; j < 7; ++j) {
    const int o = o0 + j;
    ob[(o * 3 + 0) * Nn] = accu[j][0] * sc;
    ob[(o * 3 + 1) * Nn] = accu[j][1] * sc;
    ob[(o * 3 + 2) * Nn] = accu[j][2] * sc;
  }
}

// ---------------- VN layer, fully cached: stats computes p AND d ----------------
template <int CIN, int COUT, int OT, bool HAS_BIAS>
__global__ __launch_bounds__(256) void vn_stats_pd(const float* __restrict__ X,
                                                   const float* __restrict__ Wf,
                                                   const float* __restrict__ Wd, int ws,
                                                   const float* __restrict__ biasF,
                                                   const float* __restrict__ biasD,
                                                   float* __restrict__ acc,
                                                   float* __restrict__ P,
                                                   float* __restrict__ D) {
  __shared__ float lacc[2 * OT];
  const int tid = threadIdx.x;
  if (tid < 2 * OT) lacc[tid] = 0.f;
  __syncthreads();
  const int o0 = blockIdx.y * OT;
  const int t = blockIdx.x * 256 + tid;
  const int n = t & (Nn - 1), b = t >> 13;
  const float* xb = X + (size_t)b * CIN * 3 * Nn + n;
  float* pb = P + (size_t)b * COUT * 3 * Nn + n;
  float* db = D + (size_t)b * COUT * 3 * Nn + n;
  float p[OT][3], dv[OT][3];
#pragma unroll
  for (int j = 0; j < OT; ++j)
#pragma unroll
    for (int dd = 0; dd < 3; ++dd) {
      p[j][dd] = HAS_BIAS ? biasF[((size_t)b * COUT + o0 + j) * 3 + dd] : 0.f;
      dv[j][dd] = HAS_BIAS ? biasD[((size_t)b * COUT + o0 + j) * 3 + dd] : 0.f;
    }
  for (int c = 0; c < CIN; ++c) {
    const float x0 = xb[(c * 3 + 0) * Nn];
    const float x1v = xb[(c * 3 + 1) * Nn];
    const float x2v = xb[(c * 3 + 2) * Nn];
#pragma unroll
    for (int j = 0; j < OT; ++j) {
      const float wfv = Wf[(o0 + j) * ws + c];
      p[j][0] += wfv * x0; p[j][1] += wfv * x1v; p[j][2] += wfv * x2v;
      const float wdv = Wd[(o0 + j) * ws + c];
      dv[j][0] += wdv * x0; dv[j][1] += wdv * x1v; dv[j][2] += wdv * x2v;
    }
  }
#pragma unroll
  for (int j = 0; j < OT; ++j) {
    const int o = o0 + j;
    pb[(size_t)(o * 3 + 0) * Nn] = p[j][0];
    pb[(size_t)(o * 3 + 1) * Nn] = p[j][1];
    pb[(size_t)(o * 3 + 2) * Nn] = p[j][2];
    db[(size_t)(o * 3 + 0) * Nn] = dv[j][0];
    db[(size_t)(o * 3 + 1) * Nn] = dv[j][1];
    db[(size_t)(o * 3 + 2) * Nn] = dv[j][2];
  }
#pragma unroll
  for (int j = 0; j < OT; ++j) {
    const float nrm = sqrtf(p[j][0] * p[j][0] + p[j][1] * p[j][1] + p[j][2] * p[j][2]) + EPSF;
    const float s1 = wave_sum(nrm);
    const float s2 = wave_sum(nrm * nrm);
    if ((tid & 63) == 0) { atomicAdd(&lacc[j], s1); atomicAdd(&lacc[OT + j], s2); }
  }
  __syncthreads();
  if (tid < 2 * OT) {
    const int g = (tid < OT) ? (o0 + tid) : (COUT + o0 + (tid - OT));
    atomicAdd(&acc[g], lacc[tid]);
  }
}

__device__ __forceinline__ float llr_one(float p0, float p1, float p2,
                                         float d0, float d1, float d2,
                                         float mn, float istd,
                                         float& r0o, float& r1o, float& r2o) {
  const float nrm = sqrtf(p0 * p0 + p1 * p1 + p2 * p2) + EPSF;
  const float factor = (nrm - mn) * istd / nrm;
  float r0 = p0 * factor, r1 = p1 * factor, r2 = p2 * factor;
  const float dot = r0 * d0 + r1 * d1 + r2 * d2;
  const float dsq = d0 * d0 + d1 * d1 + d2 * d2;
  const float corr = (dot < 0.f) ? dot / (dsq + EPSF) : 0.f;
  r0o = r0 - corr * d0; r1o = r1 - corr * d1; r2o = r2 - corr * d2;
  return 0.f;
}

// elementwise BN + LLR over cached p,d (float4 across n); writes P in place.
template <int COUT>
__global__ __launch_bounds__(256) void vn_llr_ew4(const float* __restrict__ acc, float cntinv,
                                                  float* __restrict__ P,
                                                  const float* __restrict__ D) {
  const int t = blockIdx.x * 256 + threadIdx.x;  // (b, o, n4)
  const int n4 = t & (Nn / 4 - 1);
  const int r = t >> 11;
  const int o = r % COUT, b = r / COUT;
  float4* pp = (float4*)(P + ((size_t)(b * COUT + o) * 3) * Nn) + n4;
  const float4* dp = (const float4*)(D + ((size_t)(b * COUT + o) * 3) * Nn) + n4;
  const float4 p0 = pp[0], p1 = pp[Nn / 4], p2 = pp[2 * (Nn / 4)];
  const float4 d0 = dp[0], d1 = dp[Nn / 4], d2 = dp[2 * (Nn / 4)];
  const float mn = acc[o] * cntinv;
  const float vr = acc[COUT + o] * cntinv - mn * mn;
  const float istd = rsqrtf(vr + BN_EPSF);
  float4 r0, r1, r2;
  llr_one(p0.x, p1.x, p2.x, d0.x, d1.x, d2.x, mn, istd, r0.x, r1.x, r2.x);
  llr_one(p0.y, p1.y, p2.y, d0.y, d1.y, d2.y, mn, istd, r0.y, r1.y, r2.y);
  llr_one(p0.z, p1.z, p2.z, d0.z, d1.z, d2.z, mn, istd, r0.z, r1.z, r2.z);
  llr_one(p0.w, p1.w, p2.w, d0.w, d1.w, d2.w, mn, istd, r0.w, r1.w, r2.w);
  pp[0] = r0;
  pp[Nn / 4] = r1;
  pp[2 * (Nn / 4)] = r2;
}

// ---------------- p-only stats (layer 3) + fallback kernels ----------------
template <int CIN, int COUT, int OT, bool HAS_BIAS>
__global__ __launch_bounds__(256) void vn_stats_pc(const float* __restrict__ X,
                                                   const float* __restrict__ Wf, int ws,
                                                   const float* __restrict__ biasF,
                                                   float* __restrict__ acc,
                                                   float* __restrict__ P) {
  __shared__ float lacc[2 * OT];
  const int tid = threadIdx.x;
  if (tid < 2 * OT) lacc[tid] = 0.f;
  __syncthreads();
  const int o0 = blockIdx.y * OT;
  const int t = blockIdx.x * 256 + tid;
  const int n = t & (Nn - 1), b = t >> 13;
  const float* xb = X + (size_t)b * CIN * 3 * Nn + n;
  float* pb = P + (size_t)b * COUT * 3 * Nn + n;
  float p[OT][3];
#pragma unroll
  for (int j = 0; j < OT; ++j)
#pragma unroll
    for (int dd = 0; dd < 3; ++dd)
      p[j][dd] = HAS_BIAS ? biasF[((size_t)b * COUT + o0 + j) * 3 + dd] : 0.f;
  for (int c = 0; c < CIN; ++c) {
    const float x0 = xb[(c * 3 + 0) * Nn];
    const float x1v = xb[(c * 3 + 1) * Nn];
    const float x2v = xb[(c * 3 + 2) * Nn];
#pragma unroll
    for (int j = 0; j < OT; ++j) {
      const float wv = Wf[(o0 + j) * ws + c];
      p[j][0] += wv * x0; p[j][1] += wv * x1v; p[j][2] += wv * x2v;
    }
  }
#pragma unroll
  for (int j = 0; j < OT; ++j) {
    const int o = o0 + j;
    pb[(size_t)(o * 3 + 0) * Nn] = p[j][0];
    pb[(size_t)(o * 3 + 1) * Nn] = p[j][1];
    pb[(size_t)(o * 3 + 2) * Nn] = p[j][2];
  }
#pragma unroll
  for (int j = 0; j < OT; ++j) {
    const float nrm = sqrtf(p[j][0] * p[j][0] + p[j][1] * p[j][1] + p[j][2] * p[j][2]) + EPSF;
    const float s1 = wave_sum(nrm);
    const float s2 = wave_sum(nrm * nrm);
    if ((tid & 63) == 0) { atomicAdd(&lacc[j], s1); atomicAdd(&lacc[OT + j], s2); }
  }
  __syncthreads();
  if (tid < 2 * OT) {
    const int g = (tid < OT) ? (o0 + tid) : (COUT + o0 + (tid - OT));
    atomicAdd(&acc[g], lacc[tid]);
  }
}

template <int CIN, int COUT, int OT, bool HAS_BIAS>
__global__ __launch_bounds__(256) void vn_apply_pc(const float* __restrict__ X,
                                                   const float* __restrict__ Wd, int ws,
                                                   const float* __restrict__ biasD,
                                                   const float* __restrict__ acc, float cntinv,
                                                   float* __restrict__ P) {
  const int o0 = blockIdx.y * OT;
  const int t = blockIdx.x * 256 + threadIdx.x;
  const int n = t & (Nn - 1), b = t >> 13;
  const float* xb = X + (size_t)b * CIN * 3 * Nn + n;
  float* pb = P + (size_t)b * COUT * 3 * Nn + n;
  float dv[OT][3];
#pragma unroll
  for (int j = 0; j < OT; ++j)
#pragma unroll
    for (int dd = 0; dd < 3; ++dd)
      dv[j][dd] = HAS_BIAS ? biasD[((size_t)b * COUT + o0 + j) * 3 + dd] : 0.f;
  for (int c = 0; c < CIN; ++c) {
    const float x0 = xb[(c * 3 + 0) * Nn];
    const float x1v = xb[(c * 3 + 1) * Nn];
    const float x2v = xb[(c * 3 + 2) * Nn];
#pragma unroll
    for (int j = 0; j < OT; ++j) {
      const float wdv = Wd[(o0 + j) * ws + c];
      dv[j][0] += wdv * x0; dv[j][1] += wdv * x1v; dv[j][2] += wdv * x2v;
    }
  }
#pragma unroll
  for (int j = 0; j < OT; ++j) {
    const int o = o0 + j;
    const float p0 = pb[(size_t)(o * 3 + 0) * Nn];
    const float p1 = pb[(size_t)(o * 3 + 1) * Nn];
    const float p2 = pb[(size_t)(o * 3 + 2) * Nn];
    const float nrm = sqrtf(p0 * p0 + p1 * p1 + p2 * p2) + EPSF;
    const float mn = acc[o] * cntinv;
    const float vr = acc[COUT + o] * cntinv - mn * mn;
    const float factor = (nrm - mn) * rsqrtf(vr + BN_EPSF) / nrm;
    float r0 = p0 * factor, r1 = p1 * factor, r2 = p2 * factor;
    const float dot = r0 * dv[j][0] + r1 * dv[j][1] + r2 * dv[j][2];
    const float dsq = dv[j][0] * dv[j][0] + dv[j][1] * dv[j][1] + dv[j][2] * dv[j][2];
    const float corr = (dot < 0.f) ? dot / (dsq + EPSF) : 0.f;
    r0 -= corr * dv[j][0]; r1 -= corr * dv[j][1]; r2 -= corr * dv[j][2];
    pb[(size_t)(o * 3 + 0) * Nn] = r0;
    pb[(size_t)(o * 3 + 1) * Nn] = r1;
    pb[(size_t)(o * 3 + 2) * Nn] = r2;
  }
}

// non-LLR layer: elementwise BN over cached p (float4 across n), in place.
template <int COUT>
__global__ __launch_bounds__(256) void vn_bn4(const float* __restrict__ acc, float cntinv,
                                              float* __restrict__ P) {
  const int t = blockIdx.x * 256 + threadIdx.x;  // (b, o, n4)
  const int n4 = t & (Nn / 4 - 1);
  const int r = t >> 11;
  const int o = r % COUT, b = r / COUT;
  float4* pp = (float4*)(P + ((size_t)(b * COUT + o) * 3) * Nn) + n4;
  const float4 p0 = pp[0], p1 = pp[Nn / 4], p2 = pp[2 * (Nn / 4)];
  const float mn = acc[o] * cntinv;
  const float vr = acc[COUT + o] * cntinv - mn * mn;
  const float istd = rsqrtf(vr + BN_EPSF);
  float4 r0, r1, r2;
#define BN_ONE(f) {                                                        \
    const float nrm = sqrtf(p0.f * p0.f + p1.f * p1.f + p2.f * p2.f) + EPSF; \
    const float factor = (nrm - mn) * istd / nrm;                          \
    r0.f = p0.f * factor; r1.f = p1.f * factor; r2.f = p2.f * factor; }
  BN_ONE(x) BN_ONE(y) BN_ONE(z) BN_ONE(w)
#undef BN_ONE
  pp[0] = r0;
  pp[Nn / 4] = r1;
  pp[2 * (Nn / 4)] = r2;
}

// ---------------- stage 5: mean over N, bias precompute, small outputs ----------------
__global__ __launch_bounds__(256) void s5_mean(const float* __restrict__ x4,
                                               float* __restrict__ xm,
                                               float* __restrict__ out) {
  const int row = blockIdx.x;  // 0..1019 = b*255 + c*3 + dd
  const int b = row / 255, rcd = row % 255;
  const float* src = x4 + (size_t)b * 255 * Nn + (size_t)rcd * Nn;
  float s = 0.f;
  for (int n = threadIdx.x; n < Nn; n += 256) s += src[n];
  s = wave_sum(s);
  __shared__ float wsum[4];
  if ((threadIdx.x & 63) == 0) wsum[threadIdx.x >> 6] = s;
  __syncthreads();
  if (threadIdx.x == 0) {
    const float mv = (wsum[0] + wsum[1] + wsum[2] + wsum[3]) * (1.f / (float)Nn);
    xm[row] = mv;
    out[2040 + row] = mv;  // x_mean_out
  }
}

__global__ __launch_bounds__(256) void s5_bias(const float* __restrict__ xm,
                                               const float* __restrict__ ws1f,
                                               const float* __restrict__ ws1d,
                                               float* __restrict__ biasF,
                                               float* __restrict__ biasD,
                                               float* __restrict__ out) {
  const int t = blockIdx.x * 256 + threadIdx.x;
  if (t < 1020) {
    const int b = t / 255, r = t % 255, o = r / 3, dd = r % 3;
    float sf = 0.f, sd = 0.f;
    for (int c = 0; c < 85; ++c) {
      const float xv = xm[(b * 85 + c) * 3 + dd];
      sf += ws1f[o * 170 + 85 + c] * xv;
      sd += ws1d[o * 170 + 85 + c] * xv;
    }
    biasF[t] = sf;
    biasD[t] = sd;
  }
  if (t < 340) {
    const int b = t / 85, c = t % 85;
    out[3060 + t] = (xm[(b * 85 + c) * 3 + 0] + xm[(b * 85 + c) * 3 + 1] +
                     xm[(b * 85 + c) * 3 + 2]) * (1.f / 3.f);  // center_loc
  }
}

// ---------------- stage 8: z3 = wlin · z2 ----------------
__global__ __launch_bounds__(256) void s8_z3(const float* __restrict__ z2,
                                             const float* __restrict__ wlin,
                                             float* __restrict__ z3) {
  const int t = blockIdx.x * 256 + threadIdx.x;
  const int n = t & (Nn - 1), b = t >> 13;
  const float* zb = z2 + (size_t)b * 42 * 3 * Nn + n;
  float accv[3][3];
#pragma unroll
  for (int o = 0; o < 3; ++o)
#pragma unroll
    for (int dd = 0; dd < 3; ++dd) accv[o][dd] = 0.f;
  for (int c = 0; c < 42; ++c) {
    const float x0 = zb[(c * 3 + 0) * Nn];
    const float x1v = zb[(c * 3 + 1) * Nn];
    const float x2v = zb[(c * 3 + 2) * Nn];
#pragma unroll
    for (int o = 0; o < 3; ++o) {
      const float wv = wlin[o * 42 + c];
      accv[o][0] += wv * x0; accv[o][1] += wv * x1v; accv[o][2] += wv * x2v;
    }
  }
  float* ob = z3 + (size_t)b * 9 * Nn + n;
#pragma unroll
  for (int o = 0; o < 3; ++o)
#pragma unroll
    for (int dd = 0; dd < 3; ++dd) ob[(o * 3 + dd) * Nn] = accv[o][dd];
}

// ---------------- stage 9: x_std + max over N ----------------
__global__ __launch_bounds__(256) void s9_max(const float* __restrict__ x4,
                                              const float* __restrict__ xm,
                                              const float* __restrict__ z3,
                                              float* __restrict__ out) {
  const int tile = blockIdx.x;  // 0..33
  const int b = blockIdx.y;
  const int i0 = tile * 5;
  const bool upper = (i0 >= 85);
  float mx[15];
#pragma unroll
  for (int r = 0; r < 15; ++r) mx[r] = -3.402823466e38f;
  float xmr[5][3];
  if (upper) {
#pragma unroll
    for (int ii = 0; ii < 5; ++ii)
#pragma unroll
      for (int j = 0; j < 3; ++j) xmr[ii][j] = xm[(b * 85 + (i0 - 85 + ii)) * 3 + j];
  }
  const float* zb = z3 + (size_t)b * 9 * Nn;
  const float* xb = x4 + (size_t)b * 255 * Nn;
  for (int n = threadIdx.x; n < Nn; n += 256) {
    float zk[3][3];
#pragma unroll
    for (int k = 0; k < 3; ++k)
#pragma unroll
      for (int j = 0; j < 3; ++j) zk[k][j] = zb[(k * 3 + j) * Nn + n];
#pragma unroll
    for (int ii = 0; ii < 5; ++ii) {
      float xj0, xj1, xj2;
      if (upper) {
        xj0 = xmr[ii][0]; xj1 = xmr[ii][1]; xj2 = xmr[ii][2];
      } else {
        xj0 = xb[((i0 + ii) * 3 + 0) * Nn + n];
        xj1 = xb[((i0 + ii) * 3 + 1) * Nn + n];
        xj2 = xb[((i0 + ii) * 3 + 2) * Nn + n];
      }
#pragma unroll
      for (int k = 0; k < 3; ++k) {
        const float v = xj0 * zk[k][0] + xj1 * zk[k][1] + xj2 * zk[k][2];
        mx[ii * 3 + k] = fmaxf(mx[ii * 3 + k], v);
      }
    }
  }
  __shared__ float red[4 * 15];
#pragma unroll
  for (int r = 0; r < 15; ++r) {
    const float v = wave_max(mx[r]);
    if ((threadIdx.x & 63) == 0) red[(threadIdx.x >> 6) * 15 + r] = v;
  }
  __syncthreads();
  if (threadIdx.x < 15) {
    const float v = fmaxf(fmaxf(red[threadIdx.x], red[15 + threadIdx.x]),
                          fmaxf(red[30 + threadIdx.x], red[45 + threadIdx.x]));
    out[b * 510 + i0 * 3 + threadIdx.x] = v;
  }
}

// ---------------- launch ----------------
extern "C" void kernel_launch(void* const* d_in, const int* in_sizes, int n_in,
                              void* d_out, int out_size, void* d_ws, size_t ws_size,
                              hipStream_t stream) {
  const float* pts   = (const float*)d_in[0];
  const float* wposf = (const float*)d_in[1];
  const float* wposd = (const float*)d_in[2];
  const float* w1f   = (const float*)d_in[3];
  const float* w1d   = (const float*)d_in[4];
  const float* w2f   = (const float*)d_in[5];
  const float* w2d   = (const float*)d_in[6];
  const float* w3    = (const float*)d_in[7];
  const float* ws1f  = (const float*)d_in[8];
  const float* ws1d  = (const float*)d_in[9];
  const float* ws2f  = (const float*)d_in[10];
  const float* ws2d  = (const float*)d_in[11];
  const float* wlin  = (const float*)d_in[12];
  float* out = (float*)d_out;
  float* wsf = (float*)d_ws;

  uint32_t* knnp0 = (uint32_t*)(wsf + KNN0_OFF);
  float* x1 = wsf + X1_OFF;
  float* x2 = wsf + X2_OFF;
  float* x3 = wsf + X3_OFF;
  float* z1 = wsf + Z1_OFF;
  float* x4 = wsf + X4_OFF;
  int* idx  = (int*)(wsf + IDX_OFF);
  float* z2 = wsf + Z2_OFF;
  float* z3 = wsf + Z3_OFF;
  float* acc = wsf + ACC_OFF;
  float* xm = wsf + XM_OFF;
  float* biasF = wsf + BF_OFF;
  float* biasD = wsf + BD_OFF;
  float* d1 = wsf + X3_OFF;   // dead region before x3 written
  float* d2 = wsf + X4_OFF;   // dead region before x4 written
  float* dext = wsf + DEXT_OFF;
  const bool ext = ws_size >= EXT_NEED;

  const float inv_sites = 1.f / (float)(Bb * Nn);

  zero_acc<<<1, 1024, 0, stream>>>(acc);
  knn_kernel<<<dim3(Nn / 256, Bb, SEG), 256, 0, stream>>>(pts, knnp0);
  merge8<<<Bb * Nn / 256, 256, 0, stream>>>(knnp0, idx);

  s1_stats<<<Bb * Nn * 5 / 256, 256, 0, stream>>>(pts, idx, wposf, acc + 0);
  s1_apply<<<dim3(Bb * Nn / 256, 3), 256, 0, stream>>>(pts, idx, wposf, wposd, acc + 0, x1);

  // layer <21,21> LLR: fused p+d stats, elementwise LLR (float4)
  vn_stats_pd<21, 21, 7, false><<<dim3(Bb * Nn / 256, 3), 256, 0, stream>>>(
      x1, w1f, w1d, 21, nullptr, nullptr, acc + 64, x2, d1);
  vn_llr_ew4<21><<<Bb * 21 * Nn / 4 / 256, 256, 0, stream>>>(acc + 64, inv_sites, x2, d1);

  // layer <21,42> LLR
  vn_stats_pd<21, 42, 7, false><<<dim3(Bb * Nn / 256, 6), 256, 0, stream>>>(
      x2, w2f, w2d, 42, nullptr, nullptr, acc + 128, x3, d2);
  vn_llr_ew4<42><<<Bb * 42 * Nn / 4 / 256, 256, 0, stream>>>(acc + 128, inv_sites, x3, d2);

  // layer <42,85> no LLR: p-only stats (OT=5, high occupancy) + elementwise BN (float4)
  vn_stats_pc<42, 85, 5, false><<<dim3(Bb * Nn / 256, 17), 256, 0, stream>>>(
      x3, w3, 42, nullptr, acc + 256, x4);
  vn_bn4<85><<<Bb * 85 * Nn / 4 / 256, 256, 0, stream>>>(acc + 256, inv_sites, x4);

  s5_mean<<<Bb * 255, 256, 0, stream>>>(x4, xm, out);
  s5_bias<<<4, 256, 0, stream>>>(xm, ws1f, ws1d, biasF, biasD, out);

  if (ext) {
    vn_stats_pd<85, 85, 5, true><<<dim3(Bb * Nn / 256, 17), 256, 0, stream>>>(
        x4, ws1f, ws1d, 170, biasF, biasD, acc + 512, z1, dext);
    vn_llr_ew4<85><<<Bb * 85 * Nn / 4 / 256, 256, 0, stream>>>(acc + 512, inv_sites, z1, dext);
    vn_stats_pd<85, 42, 7, false><<<dim3(Bb * Nn / 256, 6), 256, 0, stream>>>(
        z1, ws2f, ws2d, 85, nullptr, nullptr, acc + 768, z2, dext);
    vn_llr_ew4<42><<<Bb * 42 * Nn / 4 / 256, 256, 0, stream>>>(acc + 768, inv_sites, z2, dext);
  } else {
    vn_stats_pc<85, 85, 17, true><<<dim3(Bb * Nn / 256, 5), 256, 0, stream>>>(
        x4, ws1f, 170, biasF, acc + 512, z1);
    vn_apply_pc<85, 85, 17, true><<<dim3(Bb * Nn / 256, 5), 256, 0, stream>>>(
        x4, ws1d, 170, biasD, acc + 512, inv_sites, z1);
    vn_stats_pc<85, 42, 14, false><<<dim3(Bb * Nn / 256, 3), 256, 0, stream>>>(
        z1, ws2f, 85, nullptr, acc + 768, z2);
    vn_apply_pc<85, 42, 14, false><<<dim3(Bb * Nn / 256, 3), 256, 0, stream>>>(
        z1, ws2d, 85, nullptr, acc + 768, inv_sites, z2);
  }

  s8_z3<<<Bb * Nn / 256, 256, 0, stream>>>(z2, wlin, z3);
  s9_max<<<dim3(34, Bb), 256, 0, stream>>>(x4, xm, z3, out);
}

// Round 15
// 647.684 us; speedup vs baseline: 1.0877x; 1.0249x over previous
//
#include <hip/hip_runtime.h>
#include <cstdint>
#include <cstddef>

#define EPSF 1e-6f
#define BN_EPSF 1e-5f

constexpr int Bb = 4;
constexpr int Nn = 8192;
constexpr int KK = 20;
constexpr int SEG = 8;            // knn candidate segments
constexpr int SEGLEN = Nn / SEG;  // 1024
constexpr int BUF = 24;           // per-lane candidate buffer (LDS slots)

// ---------------- workspace layout (float elements) ----------------
constexpr size_t KNN0_OFF = 0;              // B*8*N*20 u32 = 5,242,880
constexpr size_t X1_OFF  = 0;               // B*21*3*N = 2,064,384
constexpr size_t X2_OFF  = 2064384;
constexpr size_t X3_OFF  = 4128768;         // B*42*3*N = 4,128,768 (ends 8,257,536)
constexpr size_t Z1_OFF  = 0;               // B*85*3*N = 8,355,840
constexpr size_t X4_OFF  = 8355840;         // 8,355,840
constexpr size_t IDX_OFF = 16711680;        // B*N*K ints = 655,360
constexpr size_t Z2_OFF  = 17367040;        // 4,128,768
constexpr size_t Z3_OFF  = 21495808;        // B*3*3*N = 294,912
constexpr size_t ACC_OFF = 21790720;        // 1024
constexpr size_t XM_OFF  = 21791744;        // 1020
constexpr size_t BF_OFF  = 21792764;        // 1020
constexpr size_t BD_OFF  = 21793784;        // 1020
constexpr size_t DEXT_OFF = 21795840;       // 8,355,840 (only if ws_size permits)
constexpr size_t EXT_NEED = (DEXT_OFF + 8355840) * 4;  // bytes

__device__ __forceinline__ float wave_sum(float v) {
#pragma unroll
  for (int off = 32; off; off >>= 1) v += __shfl_xor(v, off, 64);
  return v;
}
__device__ __forceinline__ float wave_max(float v) {
#pragma unroll
  for (int off = 32; off; off >>= 1) v = fmaxf(v, __shfl_xor(v, off, 64));
  return v;
}
__device__ __forceinline__ uint32_t umin32(uint32_t a, uint32_t b) { return a < b ? a : b; }
__device__ __forceinline__ uint32_t umax32(uint32_t a, uint32_t b) { return a < b ? b : a; }

// ---------------- zero accumulators ----------------
__global__ __launch_bounds__(1024) void zero_acc(float* __restrict__ a) {
  a[threadIdx.x] = 0.f;
}

// ---------------- KNN: buffered top-20, h-folded float screen (proven 186us) ----------------
__global__ __launch_bounds__(256) void knn_kernel(const float* __restrict__ pts,
                                                  uint32_t* __restrict__ knnp) {
  __shared__ float4 tile[SEGLEN];          // 16 KB (xyz + 0.5|c|^2)
  __shared__ uint32_t buf[BUF * 256];      // 24 KB
  const int tid = threadIdx.x;
  const int n = blockIdx.x * 256 + tid;
  const int b = blockIdx.y;
  const int s = blockIdx.z;
  const float* pb = pts + (size_t)b * Nn * 3;

  for (int i = tid; i < SEGLEN; i += 256) {
    const float* p = pb + (size_t)(s * SEGLEN + i) * 3;
    const float x = p[0], y = p[1], z = p[2];
    tile[i] = make_float4(x, y, z, 0.5f * (x * x + y * y + z * z));
  }
  const float qx = pb[n * 3 + 0], qy = pb[n * 3 + 1], qz = pb[n * 3 + 2];
  const float nqx = -qx, nqy = -qy, nqz = -qz;
  const float h = 0.5f * (qx * qx + qy * qy + qz * qz);
  __syncthreads();

  uint32_t keys[KK];
#pragma unroll
  for (int j = 0; j < KK; ++j) keys[j] = 0xFFFFFFFFu;

  const int base = s * SEGLEN;

#pragma unroll 4
  for (int j = 0; j < 64; ++j) {
    const float4 c = tile[j];
    float u = fmaf(nqx, c.x, fmaf(nqy, c.y, fmaf(nqz, c.z, c.w + h)));
    u = fmaxf(u, 0.f);
    uint32_t mx = (__float_as_uint(u) & 0xFFFFE000u) | (uint32_t)(base + j);
#pragma unroll
    for (int q = 0; q < KK; ++q) {
      const uint32_t mn = umin32(keys[q], mx);
      mx = umax32(keys[q], mx);
      keys[q] = mn;
    }
  }

  uint32_t thresh = keys[KK - 1];
  float thresh_up = __uint_as_float((thresh & 0xFFFFE000u) + 0x2000u);
  float th_h = thresh_up - h + 2.4e-7f * fabsf(thresh_up) + 1e-30f;
  int cnt = 0;

  for (int j0 = 64; j0 < SEGLEN; j0 += 4) {
#pragma unroll
    for (int u4 = 0; u4 < 4; ++u4) {
      const int j = j0 + u4;
      const float4 c = tile[j];
      const float up = fmaf(nqx, c.x, fmaf(nqy, c.y, fmaf(nqz, c.z, c.w)));
      if (up < th_h) {
        const float uc = fmaxf(up + h, 0.f);
        buf[cnt * 256 + tid] = (__float_as_uint(uc) & 0xFFFFE000u) | (uint32_t)(base + j);
        ++cnt;
      }
    }
    if (__any(cnt > BUF - 4)) {
#pragma unroll
      for (int i = 0; i < BUF; ++i) {
        uint32_t mx = (i < cnt) ? buf[i * 256 + tid] : 0xFFFFFFFFu;
#pragma unroll
        for (int q = 0; q < KK; ++q) {
          const uint32_t mn = umin32(keys[q], mx);
          mx = umax32(keys[q], mx);
          keys[q] = mn;
        }
      }
      cnt = 0;
      thresh = keys[KK - 1];
      thresh_up = __uint_as_float((thresh & 0xFFFFE000u) + 0x2000u);
      th_h = thresh_up - h + 2.4e-7f * fabsf(thresh_up) + 1e-30f;
    }
  }
#pragma unroll
  for (int i = 0; i < BUF; ++i) {
    uint32_t mx = (i < cnt) ? buf[i * 256 + tid] : 0xFFFFFFFFu;
#pragma unroll
    for (int q = 0; q < KK; ++q) {
      const uint32_t mn = umin32(keys[q], mx);
      mx = umax32(keys[q], mx);
      keys[q] = mn;
    }
  }

  uint32_t* op = knnp + ((size_t)(b * SEG + s) * KK) * Nn + n;
#pragma unroll
  for (int j = 0; j < KK; ++j) op[(size_t)j * Nn] = keys[j];
}

// ---------------- single-pass 8-way merge (keys unique -> deterministic) ----------------
__global__ __launch_bounds__(256) void merge8(const uint32_t* __restrict__ in,
                                              int* __restrict__ idx) {
  const int t = blockIdx.x * 256 + threadIdx.x;  // B*N threads
  const int n = t & (Nn - 1), b = t >> 13;
  const uint32_t* base = in + ((size_t)(b * SEG) * KK) * Nn + n;
  uint32_t h[SEG];
  int ii[SEG];
#pragma unroll
  for (int s = 0; s < SEG; ++s) {
    h[s] = base[(size_t)s * KK * Nn];
    ii[s] = 1;
  }
  int* op = idx + (size_t)t * KK;
#pragma unroll
  for (int m = 0; m < KK; ++m) {
    uint32_t k = h[0];
#pragma unroll
    for (int s = 1; s < SEG; ++s) k = umin32(k, h[s]);
    op[m] = (int)(k & 8191u);
#pragma unroll
    for (int s = 0; s < SEG; ++s) {
      if (h[s] == k) {
        h[s] = (ii[s] < KK) ? base[(size_t)s * KK * Nn + (size_t)ii[s] * Nn] : 0xFFFFFFFFu;
        ii[s]++;
      }
    }
  }
}

// ---------------- stage 1: feature-cross + LLR(21) ----------------
__global__ __launch_bounds__(256) void s1_stats(const float* __restrict__ pts,
                                                const int* __restrict__ idx,
                                                const float* __restrict__ wf,
                                                float* __restrict__ acc) {
  __shared__ float lacc[42];
  const int tid = threadIdx.x;
  for (int i = tid; i < 42; i += 256) lacc[i] = 0.f;
  __syncthreads();
  const int t = blockIdx.x * 256 + tid;  // 0..B*N*5-1
  const int site = t / 5;
  const int kq = (t % 5) * 4;
  const int n = site & (Nn - 1), b = site >> 13;
  const float* pb = pts + (size_t)b * Nn * 3;
  const float cx = pb[n * 3 + 0], cy = pb[n * 3 + 1], cz = pb[n * 3 + 2];
  float s1a[21], s2a[21];
#pragma unroll
  for (int o = 0; o < 21; ++o) { s1a[o] = 0.f; s2a[o] = 0.f; }
#pragma unroll
  for (int k = kq; k < kq + 4; ++k) {
    const int m = idx[(size_t)site * KK + k];
    const float ax = pb[m * 3 + 0], ay = pb[m * 3 + 1], az = pb[m * 3 + 2];
    const float e0x = ax - cx, e0y = ay - cy, e0z = az - cz;
    const float e2x = ay * cz - az * cy, e2y = az * cx - ax * cz, e2z = ax * cy - ay * cx;
#pragma unroll
    for (int o = 0; o < 21; ++o) {
      const float w0 = wf[o * 3 + 0], w1 = wf[o * 3 + 1], w2 = wf[o * 3 + 2];
      const float px = w0 * e0x + w1 * cx + w2 * e2x;
      const float py = w0 * e0y + w1 * cy + w2 * e2y;
      const float pz = w0 * e0z + w1 * cz + w2 * e2z;
      const float nrm = sqrtf(px * px + py * py + pz * pz) + EPSF;
      s1a[o] += nrm;
      s2a[o] += nrm * nrm;
    }
  }
#pragma unroll
  for (int o = 0; o < 21; ++o) {
    const float s1 = wave_sum(s1a[o]);
    const float s2 = wave_sum(s2a[o]);
    if ((tid & 63) == 0) { atomicAdd(&lacc[o], s1); atomicAdd(&lacc[21 + o], s2); }
  }
  __syncthreads();
  for (int i = tid; i < 42; i += 256) atomicAdd(&acc[i], lacc[i]);
}

// tile of 7 output channels per block (blockIdx.y)
__global__ __launch_bounds__(256) void s1_apply(const float* __restrict__ pts,
                                                const int* __restrict__ idx,
                                                const float* __restrict__ wf,
                                                const float* __restrict__ wd,
                                                const float* __restrict__ acc,
                                                float* __restrict__ x1) {
  const int t = blockIdx.x * 256 + threadIdx.x;  // site 0..B*N-1
  const int o0 = blockIdx.y * 7;
  const int n = t & (Nn - 1), b = t >> 13;
  const float* pb = pts + (size_t)b * Nn * 3;
  const float cx = pb[n * 3 + 0], cy = pb[n * 3 + 1], cz = pb[n * 3 + 2];
  const float inv_cnt = 1.f / (float)(Bb * Nn * KK);
  float meano[7], istdo[7];
#pragma unroll
  for (int j = 0; j < 7; ++j) {
    const float mn = acc[o0 + j] * inv_cnt;
    const float vr = acc[21 + o0 + j] * inv_cnt - mn * mn;
    meano[j] = mn;
    istdo[j] = rsqrtf(vr + BN_EPSF);
  }
  float accu[7][3];
#pragma unroll
  for (int j = 0; j < 7; ++j) { accu[j][0] = 0.f; accu[j][1] = 0.f; accu[j][2] = 0.f; }
  for (int k = 0; k < KK; ++k) {
    const int m = idx[(size_t)t * KK + k];
    const float ax = pb[m * 3 + 0], ay = pb[m * 3 + 1], az = pb[m * 3 + 2];
    const float e0x = ax - cx, e0y = ay - cy, e0z = az - cz;
    const float e2x = ay * cz - az * cy, e2y = az * cx - ax * cz, e2z = ax * cy - ay * cx;
#pragma unroll
    for (int j = 0; j < 7; ++j) {
      const int o = o0 + j;
      const float wf0 = wf[o * 3 + 0], wf1 = wf[o * 3 + 1], wf2 = wf[o * 3 + 2];
      const float px = wf0 * e0x + wf1 * cx + wf2 * e2x;
      const float py = wf0 * e0y + wf1 * cy + wf2 * e2y;
      const float pz = wf0 * e0z + wf1 * cz + wf2 * e2z;
      const float nrm = sqrtf(px * px + py * py + pz * pz) + EPSF;
      const float factor = (nrm - meano[j]) * istdo[j] / nrm;
      const float q0 = px * factor, q1 = py * factor, q2 = pz * factor;
      const float wd0 = wd[o * 3 + 0], wd1 = wd[o * 3 + 1], wd2 = wd[o * 3 + 2];
      const float dx = wd0 * e0x + wd1 * cx + wd2 * e2x;
      const float dy = wd0 * e0y + wd1 * cy + wd2 * e2y;
      const float dz = wd0 * e0z + wd1 * cz + wd2 * e2z;
      const float dot = q0 * dx + q1 * dy + q2 * dz;
      const float dsq = dx * dx + dy * dy + dz * dz;
      const float corr = (dot < 0.f) ? dot / (dsq + EPSF) : 0.f;
      accu[j][0] += q0 - corr * dx;
      accu[j][1] += q1 - corr * dy;
      accu[j][2] += q2 - corr * dz;
    }
  }
  const float sc = 1.f / (float)KK;
  float* ob = x1 + (size_t)b * 21 * 3 * Nn + n;
#pragma unroll
  for (int j = 0; j < 7; ++j) {
    const int o = o0 + j;
    ob[(o * 3 + 0) * Nn] = accu[j][0] * sc;
    ob[(o * 3 + 1) * Nn] = accu[j][1] * sc;
    ob[(o * 3 + 2) * Nn] = accu[j][2] * sc;
  }
}

// ---------------- VN layer (scalar): stats computes p AND d ----------------
template <int CIN, int COUT, int OT, bool HAS_BIAS>
__global__ __launch_bounds__(256) void vn_stats_pd(const float* __restrict__ X,
                                                   const float* __restrict__ Wf,
                                                   const float* __restrict__ Wd, int ws,
                                                   const float* __restrict__ biasF,
                                                   const float* __restrict__ biasD,
                                                   float* __restrict__ acc,
                                                   float* __restrict__ P,
                                                   float* __restrict__ D) {
  __shared__ float lacc[2 * OT];
  const int tid = threadIdx.x;
  if (tid < 2 * OT) lacc[tid] = 0.f;
  __syncthreads();
  const int o0 = blockIdx.y * OT;
  const int t = blockIdx.x * 256 + tid;
  const int n = t & (Nn - 1), b = t >> 13;
  const float* xb = X + (size_t)b * CIN * 3 * Nn + n;
  float* pb = P + (size_t)b * COUT * 3 * Nn + n;
  float* db = D + (size_t)b * COUT * 3 * Nn + n;
  float p[OT][3], dv[OT][3];
#pragma unroll
  for (int j = 0; j < OT; ++j)
#pragma unroll
    for (int dd = 0; dd < 3; ++dd) {
      p[j][dd] = HAS_BIAS ? biasF[((size_t)b * COUT + o0 + j) * 3 + dd] : 0.f;
      dv[j][dd] = HAS_BIAS ? biasD[((size_t)b * COUT + o0 + j) * 3 + dd] : 0.f;
    }
  for (int c = 0; c < CIN; ++c) {
    const float x0 = xb[(c * 3 + 0) * Nn];
    const float x1v = xb[(c * 3 + 1) * Nn];
    const float x2v = xb[(c * 3 + 2) * Nn];
#pragma unroll
    for (int j = 0; j < OT; ++j) {
      const float wfv = Wf[(o0 + j) * ws + c];
      p[j][0] += wfv * x0; p[j][1] += wfv * x1v; p[j][2] += wfv * x2v;
      const float wdv = Wd[(o0 + j) * ws + c];
      dv[j][0] += wdv * x0; dv[j][1] += wdv * x1v; dv[j][2] += wdv * x2v;
    }
  }
#pragma unroll
  for (int j = 0; j < OT; ++j) {
    const int o = o0 + j;
    pb[(size_t)(o * 3 + 0) * Nn] = p[j][0];
    pb[(size_t)(o * 3 + 1) * Nn] = p[j][1];
    pb[(size_t)(o * 3 + 2) * Nn] = p[j][2];
    db[(size_t)(o * 3 + 0) * Nn] = dv[j][0];
    db[(size_t)(o * 3 + 1) * Nn] = dv[j][1];
    db[(size_t)(o * 3 + 2) * Nn] = dv[j][2];
  }
#pragma unroll
  for (int j = 0; j < OT; ++j) {
    const float nrm = sqrtf(p[j][0] * p[j][0] + p[j][1] * p[j][1] + p[j][2] * p[j][2]) + EPSF;
    const float s1 = wave_sum(nrm);
    const float s2 = wave_sum(nrm * nrm);
    if ((tid & 63) == 0) { atomicAdd(&lacc[j], s1); atomicAdd(&lacc[OT + j], s2); }
  }
  __syncthreads();
  if (tid < 2 * OT) {
    const int g = (tid < OT) ? (o0 + tid) : (COUT + o0 + (tid - OT));
    atomicAdd(&acc[g], lacc[tid]);
  }
}

// ---------------- VN layer (float2 across n): stats computes p AND d ----------------
template <int CIN, int COUT, int OT, bool HAS_BIAS>
__global__ __launch_bounds__(256) void vn_stats_pd2(const float* __restrict__ X,
                                                    const float* __restrict__ Wf,
                                                    const float* __restrict__ Wd, int ws,
                                                    const float* __restrict__ biasF,
                                                    const float* __restrict__ biasD,
                                                    float* __restrict__ acc,
                                                    float* __restrict__ P,
                                                    float* __restrict__ D) {
  __shared__ float lacc[2 * OT];
  const int tid = threadIdx.x;
  if (tid < 2 * OT) lacc[tid] = 0.f;
  __syncthreads();
  const int o0 = blockIdx.y * OT;
  const int sp = blockIdx.x * 256 + tid;        // site-pair
  const int n = (sp & (Nn / 2 - 1)) * 2, b = sp >> 12;
  const float* xb = X + (size_t)b * CIN * 3 * Nn + n;
  float* pb = P + (size_t)b * COUT * 3 * Nn + n;
  float* db = D + (size_t)b * COUT * 3 * Nn + n;
  float2 p[OT][3], dv[OT][3];
#pragma unroll
  for (int j = 0; j < OT; ++j)
#pragma unroll
    for (int dd = 0; dd < 3; ++dd) {
      const float bf = HAS_BIAS ? biasF[((size_t)b * COUT + o0 + j) * 3 + dd] : 0.f;
      const float bd = HAS_BIAS ? biasD[((size_t)b * COUT + o0 + j) * 3 + dd] : 0.f;
      p[j][dd] = make_float2(bf, bf);
      dv[j][dd] = make_float2(bd, bd);
    }
  for (int c = 0; c < CIN; ++c) {
    const float2 x0 = *(const float2*)(xb + (size_t)(c * 3 + 0) * Nn);
    const float2 x1v = *(const float2*)(xb + (size_t)(c * 3 + 1) * Nn);
    const float2 x2v = *(const float2*)(xb + (size_t)(c * 3 + 2) * Nn);
#pragma unroll
    for (int j = 0; j < OT; ++j) {
      const float wfv = Wf[(o0 + j) * ws + c];
      p[j][0].x += wfv * x0.x;  p[j][0].y += wfv * x0.y;
      p[j][1].x += wfv * x1v.x; p[j][1].y += wfv * x1v.y;
      p[j][2].x += wfv * x2v.x; p[j][2].y += wfv * x2v.y;
      const float wdv = Wd[(o0 + j) * ws + c];
      dv[j][0].x += wdv * x0.x;  dv[j][0].y += wdv * x0.y;
      dv[j][1].x += wdv * x1v.x; dv[j][1].y += wdv * x1v.y;
      dv[j][2].x += wdv * x2v.x; dv[j][2].y += wdv * x2v.y;
    }
  }
#pragma unroll
  for (int j = 0; j < OT; ++j) {
    const int o = o0 + j;
    *(float2*)(pb + (size_t)(o * 3 + 0) * Nn) = p[j][0];
    *(float2*)(pb + (size_t)(o * 3 + 1) * Nn) = p[j][1];
    *(float2*)(pb + (size_t)(o * 3 + 2) * Nn) = p[j][2];
    *(float2*)(db + (size_t)(o * 3 + 0) * Nn) = dv[j][0];
    *(float2*)(db + (size_t)(o * 3 + 1) * Nn) = dv[j][1];
    *(float2*)(db + (size_t)(o * 3 + 2) * Nn) = dv[j][2];
  }
#pragma unroll
  for (int j = 0; j < OT; ++j) {
    const float n0 = sqrtf(p[j][0].x * p[j][0].x + p[j][1].x * p[j][1].x + p[j][2].x * p[j][2].x) + EPSF;
    const float n1 = sqrtf(p[j][0].y * p[j][0].y + p[j][1].y * p[j][1].y + p[j][2].y * p[j][2].y) + EPSF;
    const float s1 = wave_sum(n0 + n1);
    const float s2 = wave_sum(n0 * n0 + n1 * n1);
    if ((tid & 63) == 0) { atomicAdd(&lacc[j], s1); atomicAdd(&lacc[OT + j], s2); }
  }
  __syncthreads();
  if (tid < 2 * OT) {
    const int g = (tid < OT) ? (o0 + tid) : (COUT + o0 + (tid - OT));
    atomicAdd(&acc[g], lacc[tid]);
  }
}

__device__ __forceinline__ float llr_one(float p0, float p1, float p2,
                                         float d0, float d1, float d2,
                                         float mn, float istd,
                                         float& r0o, float& r1o, float& r2o) {
  const float nrm = sqrtf(p0 * p0 + p1 * p1 + p2 * p2) + EPSF;
  const float factor = (nrm - mn) * istd / nrm;
  float r0 = p0 * factor, r1 = p1 * factor, r2 = p2 * factor;
  const float dot = r0 * d0 + r1 * d1 + r2 * d2;
  const float dsq = d0 * d0 + d1 * d1 + d2 * d2;
  const float corr = (dot < 0.f) ? dot / (dsq + EPSF) : 0.f;
  r0o = r0 - corr * d0; r1o = r1 - corr * d1; r2o = r2 - corr * d2;
  return 0.f;
}

// elementwise BN + LLR over cached p,d (float4 across n); writes P in place.
template <int COUT>
__global__ __launch_bounds__(256) void vn_llr_ew4(const float* __restrict__ acc, float cntinv,
                                                  float* __restrict__ P,
                                                  const float* __restrict__ D) {
  const int t = blockIdx.x * 256 + threadIdx.x;  // (b, o, n4)
  const int n4 = t & (Nn / 4 - 1);
  const int r = t >> 11;
  const int o = r % COUT, b = r / COUT;
  float4* pp = (float4*)(P + ((size_t)(b * COUT + o) * 3) * Nn) + n4;
  const float4* dp = (const float4*)(D + ((size_t)(b * COUT + o) * 3) * Nn) + n4;
  const float4 p0 = pp[0], p1 = pp[Nn / 4], p2 = pp[2 * (Nn / 4)];
  const float4 d0 = dp[0], d1 = dp[Nn / 4], d2 = dp[2 * (Nn / 4)];
  const float mn = acc[o] * cntinv;
  const float vr = acc[COUT + o] * cntinv - mn * mn;
  const float istd = rsqrtf(vr + BN_EPSF);
  float4 r0, r1, r2;
  llr_one(p0.x, p1.x, p2.x, d0.x, d1.x, d2.x, mn, istd, r0.x, r1.x, r2.x);
  llr_one(p0.y, p1.y, p2.y, d0.y, d1.y, d2.y, mn, istd, r0.y, r1.y, r2.y);
  llr_one(p0.z, p1.z, p2.z, d0.z, d1.z, d2.z, mn, istd, r0.z, r1.z, r2.z);
  llr_one(p0.w, p1.w, p2.w, d0.w, d1.w, d2.w, mn, istd, r0.w, r1.w, r2.w);
  pp[0] = r0;
  pp[Nn / 4] = r1;
  pp[2 * (Nn / 4)] = r2;
}

// ---------------- p-only stats: scalar + float2 variants ----------------
template <int CIN, int COUT, int OT, bool HAS_BIAS>
__global__ __launch_bounds__(256) void vn_stats_pc(const float* __restrict__ X,
                                                   const float* __restrict__ Wf, int ws,
                                                   const float* __restrict__ biasF,
                                                   float* __restrict__ acc,
                                                   float* __restrict__ P) {
  __shared__ float lacc[2 * OT];
  const int tid = threadIdx.x;
  if (tid < 2 * OT) lacc[tid] = 0.f;
  __syncthreads();
  const int o0 = blockIdx.y * OT;
  const int t = blockIdx.x * 256 + tid;
  const int n = t & (Nn - 1), b = t >> 13;
  const float* xb = X + (size_t)b * CIN * 3 * Nn + n;
  float* pb = P + (size_t)b * COUT * 3 * Nn + n;
  float p[OT][3];
#pragma unroll
  for (int j = 0; j < OT; ++j)
#pragma unroll
    for (int dd = 0; dd < 3; ++dd)
      p[j][dd] = HAS_BIAS ? biasF[((size_t)b * COUT + o0 + j) * 3 + dd] : 0.f;
  for (int c = 0; c < CIN; ++c) {
    const float x0 = xb[(c * 3 + 0) * Nn];
    const float x1v = xb[(c * 3 + 1) * Nn];
    const float x2v = xb[(c * 3 + 2) * Nn];
#pragma unroll
    for (int j = 0; j < OT; ++j) {
      const float wv = Wf[(o0 + j) * ws + c];
      p[j][0] += wv * x0; p[j][1] += wv * x1v; p[j][2] += wv * x2v;
    }
  }
#pragma unroll
  for (int j = 0; j < OT; ++j) {
    const int o = o0 + j;
    pb[(size_t)(o * 3 + 0) * Nn] = p[j][0];
    pb[(size_t)(o * 3 + 1) * Nn] = p[j][1];
    pb[(size_t)(o * 3 + 2) * Nn] = p[j][2];
  }
#pragma unroll
  for (int j = 0; j < OT; ++j) {
    const float nrm = sqrtf(p[j][0] * p[j][0] + p[j][1] * p[j][1] + p[j][2] * p[j][2]) + EPSF;
    const float s1 = wave_sum(nrm);
    const float s2 = wave_sum(nrm * nrm);
    if ((tid & 63) == 0) { atomicAdd(&lacc[j], s1); atomicAdd(&lacc[OT + j], s2); }
  }
  __syncthreads();
  if (tid < 2 * OT) {
    const int g = (tid < OT) ? (o0 + tid) : (COUT + o0 + (tid - OT));
    atomicAdd(&acc[g], lacc[tid]);
  }
}

template <int CIN, int COUT, int OT, bool HAS_BIAS>
__global__ __launch_bounds__(256) void vn_stats_pc2(const float* __restrict__ X,
                                                    const float* __restrict__ Wf, int ws,
                                                    const float* __restrict__ biasF,
                                                    float* __restrict__ acc,
                                                    float* __restrict__ P) {
  __shared__ float lacc[2 * OT];
  const int tid = threadIdx.x;
  if (tid < 2 * OT) lacc[tid] = 0.f;
  __syncthreads();
  const int o0 = blockIdx.y * OT;
  const int sp = blockIdx.x * 256 + tid;        // site-pair
  const int n = (sp & (Nn / 2 - 1)) * 2, b = sp >> 12;
  const float* xb = X + (size_t)b * CIN * 3 * Nn + n;
  float* pb = P + (size_t)b * COUT * 3 * Nn + n;
  float2 p[OT][3];
#pragma unroll
  for (int j = 0; j < OT; ++j)
#pragma unroll
    for (int dd = 0; dd < 3; ++dd) {
      const float bf = HAS_BIAS ? biasF[((size_t)b * COUT + o0 + j) * 3 + dd] : 0.f;
      p[j][dd] = make_float2(bf, bf);
    }
  for (int c = 0; c < CIN; ++c) {
    const float2 x0 = *(const float2*)(xb + (size_t)(c * 3 + 0) * Nn);
    const float2 x1v = *(const float2*)(xb + (size_t)(c * 3 + 1) * Nn);
    const float2 x2v = *(const float2*)(xb + (size_t)(c * 3 + 2) * Nn);
#pragma unroll
    for (int j = 0; j < OT; ++j) {
      const float wv = Wf[(o0 + j) * ws + c];
      p[j][0].x += wv * x0.x;  p[j][0].y += wv * x0.y;
      p[j][1].x += wv * x1v.x; p[j][1].y += wv * x1v.y;
      p[j][2].x += wv * x2v.x; p[j][2].y += wv * x2v.y;
    }
  }
#pragma unroll
  for (int j = 0; j < OT; ++j) {
    const int o = o0 + j;
    *(float2*)(pb + (size_t)(o * 3 + 0) * Nn) = p[j][0];
    *(float2*)(pb + (size_t)(o * 3 + 1) * Nn) = p[j][1];
    *(float2*)(pb + (size_t)(o * 3 + 2) * Nn) = p[j][2];
  }
#pragma unroll
  for (int j = 0; j < OT; ++j) {
    const float n0 = sqrtf(p[j][0].x * p[j][0].x + p[j][1].x * p[j][1].x + p[j][2].x * p[j][2].x) + EPSF;
    const float n1 = sqrtf(p[j][0].y * p[j][0].y + p[j][1].y * p[j][1].y + p[j][2].y * p[j][2].y) + EPSF;
    const float s1 = wave_sum(n0 + n1);
    const float s2 = wave_sum(n0 * n0 + n1 * n1);
    if ((tid & 63) == 0) { atomicAdd(&lacc[j], s1); atomicAdd(&lacc[OT + j], s2); }
  }
  __syncthreads();
  if (tid < 2 * OT) {
    const int g = (tid < OT) ? (o0 + tid) : (COUT + o0 + (tid - OT));
    atomicAdd(&acc[g], lacc[tid]);
  }
}

template <int CIN, int COUT, int OT, bool HAS_BIAS>
__global__ __launch_bounds__(256) void vn_apply_pc(const float* __restrict__ X,
                                                   const float* __restrict__ Wd, int ws,
                                                   const float* __restrict__ biasD,
                                                   const float* __restrict__ acc, float cntinv,
                                                   float* __restrict__ P) {
  const int o0 = blockIdx.y * OT;
  const int t = blockIdx.x * 256 + threadIdx.x;
  const int n = t & (Nn - 1), b = t >> 13;
  const float* xb = X + (size_t)b * CIN * 3 * Nn + n;
  float* pb = P + (size_t)b * COUT * 3 * Nn + n;
  float dv[OT][3];
#pragma unroll
  for (int j = 0; j < OT; ++j)
#pragma unroll
    for (int dd = 0; dd < 3; ++dd)
      dv[j][dd] = HAS_BIAS ? biasD[((size_t)b * COUT + o0 + j) * 3 + dd] : 0.f;
  for (int c = 0; c < CIN; ++c) {
    const float x0 = xb[(c * 3 + 0) * Nn];
    const float x1v = xb[(c * 3 + 1) * Nn];
    const float x2v = xb[(c * 3 + 2) * Nn];
#pragma unroll
    for (int j = 0; j < OT; ++j) {
      const float wdv = Wd[(o0 + j) * ws + c];
      dv[j][0] += wdv * x0; dv[j][1] += wdv * x1v; dv[j][2] += wdv * x2v;
    }
  }
#pragma unroll
  for (int j = 0; j < OT; ++j) {
    const int o = o0 + j;
    const float p0 = pb[(size_t)(o * 3 + 0) * Nn];
    const float p1 = pb[(size_t)(o * 3 + 1) * Nn];
    const float p2 = pb[(size_t)(o * 3 + 2) * Nn];
    const float nrm = sqrtf(p0 * p0 + p1 * p1 + p2 * p2) + EPSF;
    const float mn = acc[o] * cntinv;
    const float vr = acc[COUT + o] * cntinv - mn * mn;
    const float factor = (nrm - mn) * rsqrtf(vr + BN_EPSF) / nrm;
    float r0 = p0 * factor, r1 = p1 * factor, r2 = p2 * factor;
    const float dot = r0 * dv[j][0] + r1 * dv[j][1] + r2 * dv[j][2];
    const float dsq = dv[j][0] * dv[j][0] + dv[j][1] * dv[j][1] + dv[j][2] * dv[j][2];
    const float corr = (dot < 0.f) ? dot / (dsq + EPSF) : 0.f;
    r0 -= corr * dv[j][0]; r1 -= corr * dv[j][1]; r2 -= corr * dv[j][2];
    pb[(size_t)(o * 3 + 0) * Nn] = r0;
    pb[(size_t)(o * 3 + 1) * Nn] = r1;
    pb[(size_t)(o * 3 + 2) * Nn] = r2;
  }
}

// non-LLR layer: elementwise BN over cached p (float4 across n), in place.
template <int COUT>
__global__ __launch_bounds__(256) void vn_bn4(const float* __restrict__ acc, float cntinv,
                                              float* __restrict__ P) {
  const int t = blockIdx.x * 256 + threadIdx.x;  // (b, o, n4)
  const int n4 = t & (Nn / 4 - 1);
  const int r = t >> 11;
  const int o = r % COUT, b = r / COUT;
  float4* pp = (float4*)(P + ((size_t)(b * COUT + o) * 3) * Nn) + n4;
  const float4 p0 = pp[0], p1 = pp[Nn / 4], p2 = pp[2 * (Nn / 4)];
  const float mn = acc[o] * cntinv;
  const float vr = acc[COUT + o] * cntinv - mn * mn;
  const float istd = rsqrtf(vr + BN_EPSF);
  float4 r0, r1, r2;
#define BN_ONE(f) {                                                        \
    const float nrm = sqrtf(p0.f * p0.f + p1.f * p1.f + p2.f * p2.f) + EPSF; \
    const float factor = (nrm - mn) * istd / nrm;                          \
    r0.f = p0.f * factor; r1.f = p1.f * factor; r2.f = p2.f * factor; }
  BN_ONE(x) BN_ONE(y) BN_ONE(z) BN_ONE(w)
#undef BN_ONE
  pp[0] = r0;
  pp[Nn / 4] = r1;
  pp[2 * (Nn / 4)] = r2;
}

// ---------------- stage 5: mean over N, bias precompute, small outputs ----------------
__global__ __launch_bounds__(256) void s5_mean(const float* __restrict__ x4,
                                               float* __restrict__ xm,
                                               float* __restrict__ out) {
  const int row = blockIdx.x;  // 0..1019 = b*255 + c*3 + dd
  const int b = row / 255, rcd = row % 255;
  const float* src = x4 + (size_t)b * 255 * Nn + (size_t)rcd * Nn;
  float s = 0.f;
  for (int n = threadIdx.x; n < Nn; n += 256) s += src[n];
  s = wave_sum(s);
  __shared__ float wsum[4];
  if ((threadIdx.x & 63) == 0) wsum[threadIdx.x >> 6] = s;
  __syncthreads();
  if (threadIdx.x == 0) {
    const float mv = (wsum[0] + wsum[1] + wsum[2] + wsum[3]) * (1.f / (float)Nn);
    xm[row] = mv;
    out[2040 + row] = mv;  // x_mean_out
  }
}

__global__ __launch_bounds__(256) void s5_bias(const float* __restrict__ xm,
                                               const float* __restrict__ ws1f,
                                               const float* __restrict__ ws1d,
                                               float* __restrict__ biasF,
                                               float* __restrict__ biasD,
                                               float* __restrict__ out) {
  const int t = blockIdx.x * 256 + threadIdx.x;
  if (t < 1020) {
    const int b = t / 255, r = t % 255, o = r / 3, dd = r % 3;
    float sf = 0.f, sd = 0.f;
    for (int c = 0; c < 85; ++c) {
      const float xv = xm[(b * 85 + c) * 3 + dd];
      sf += ws1f[o * 170 + 85 + c] * xv;
      sd += ws1d[o * 170 + 85 + c] * xv;
    }
    biasF[t] = sf;
    biasD[t] = sd;
  }
  if (t < 340) {
    const int b = t / 85, c = t % 85;
    out[3060 + t] = (xm[(b * 85 + c) * 3 + 0] + xm[(b * 85 + c) * 3 + 1] +
                     xm[(b * 85 + c) * 3 + 2]) * (1.f / 3.f);  // center_loc
  }
}

// ---------------- stage 8: z3 = wlin · z2 ----------------
__global__ __launch_bounds__(256) void s8_z3(const float* __restrict__ z2,
                                             const float* __restrict__ wlin,
                                             float* __restrict__ z3) {
  const int t = blockIdx.x * 256 + threadIdx.x;
  const int n = t & (Nn - 1), b = t >> 13;
  const float* zb = z2 + (size_t)b * 42 * 3 * Nn + n;
  float accv[3][3];
#pragma unroll
  for (int o = 0; o < 3; ++o)
#pragma unroll
    for (int dd = 0; dd < 3; ++dd) accv[o][dd] = 0.f;
  for (int c = 0; c < 42; ++c) {
    const float x0 = zb[(c * 3 + 0) * Nn];
    const float x1v = zb[(c * 3 + 1) * Nn];
    const float x2v = zb[(c * 3 + 2) * Nn];
#pragma unroll
    for (int o = 0; o < 3; ++o) {
      const float wv = wlin[o * 42 + c];
      accv[o][0] += wv * x0; accv[o][1] += wv * x1v; accv[o][2] += wv * x2v;
    }
  }
  float* ob = z3 + (size_t)b * 9 * Nn + n;
#pragma unroll
  for (int o = 0; o < 3; ++o)
#pragma unroll
    for (int dd = 0; dd < 3; ++dd) ob[(o * 3 + dd) * Nn] = accv[o][dd];
}

// ---------------- stage 9: x_std + max over N ----------------
__global__ __launch_bounds__(256) void s9_max(const float* __restrict__ x4,
                                              const float* __restrict__ xm,
                                              const float* __restrict__ z3,
                                              float* __restrict__ out) {
  const int tile = blockIdx.x;  // 0..33
  const int b = blockIdx.y;
  const int i0 = tile * 5;
  const bool upper = (i0 >= 85);
  float mx[15];
#pragma unroll
  for (int r = 0; r < 15; ++r) mx[r] = -3.402823466e38f;
  float xmr[5][3];
  if (upper) {
#pragma unroll
    for (int ii = 0; ii < 5; ++ii)
#pragma unroll
      for (int j = 0; j < 3; ++j) xmr[ii][j] = xm[(b * 85 + (i0 - 85 + ii)) * 3 + j];
  }
  const float* zb = z3 + (size_t)b * 9 * Nn;
  const float* xb = x4 + (size_t)b * 255 * Nn;
  for (int n = threadIdx.x; n < Nn; n += 256) {
    float zk[3][3];
#pragma unroll
    for (int k = 0; k < 3; ++k)
#pragma unroll
      for (int j = 0; j < 3; ++j) zk[k][j] = zb[(k * 3 + j) * Nn + n];
#pragma unroll
    for (int ii = 0; ii < 5; ++ii) {
      float xj0, xj1, xj2;
      if (upper) {
        xj0 = xmr[ii][0]; xj1 = xmr[ii][1]; xj2 = xmr[ii][2];
      } else {
        xj0 = xb[((i0 + ii) * 3 + 0) * Nn + n];
        xj1 = xb[((i0 + ii) * 3 + 1) * Nn + n];
        xj2 = xb[((i0 + ii) * 3 + 2) * Nn + n];
      }
#pragma unroll
      for (int k = 0; k < 3; ++k) {
        const float v = xj0 * zk[k][0] + xj1 * zk[k][1] + xj2 * zk[k][2];
        mx[ii * 3 + k] = fmaxf(mx[ii * 3 + k], v);
      }
    }
  }
  __shared__ float red[4 * 15];
#pragma unroll
  for (int r = 0; r < 15; ++r) {
    const float v = wave_max(mx[r]);
    if ((threadIdx.x & 63) == 0) red[(threadIdx.x >> 6) * 15 + r] = v;
  }
  __syncthreads();
  if (threadIdx.x < 15) {
    const float v = fmaxf(fmaxf(red[threadIdx.x], red[15 + threadIdx.x]),
                          fmaxf(red[30 + threadIdx.x], red[45 + threadIdx.x]));
    out[b * 510 + i0 * 3 + threadIdx.x] = v;
  }
}

// ---------------- launch ----------------
extern "C" void kernel_launch(void* const* d_in, const int* in_sizes, int n_in,
                              void* d_out, int out_size, void* d_ws, size_t ws_size,
                              hipStream_t stream) {
  const float* pts   = (const float*)d_in[0];
  const float* wposf = (const float*)d_in[1];
  const float* wposd = (const float*)d_in[2];
  const float* w1f   = (const float*)d_in[3];
  const float* w1d   = (const float*)d_in[4];
  const float* w2f   = (const float*)d_in[5];
  const float* w2d   = (const float*)d_in[6];
  const float* w3    = (const float*)d_in[7];
  const float* ws1f  = (const float*)d_in[8];
  const float* ws1d  = (const float*)d_in[9];
  const float* ws2f  = (const float*)d_in[10];
  const float* ws2d  = (const float*)d_in[11];
  const float* wlin  = (const float*)d_in[12];
  float* out = (float*)d_out;
  float* wsf = (float*)d_ws;

  uint32_t* knnp0 = (uint32_t*)(wsf + KNN0_OFF);
  float* x1 = wsf + X1_OFF;
  float* x2 = wsf + X2_OFF;
  float* x3 = wsf + X3_OFF;
  float* z1 = wsf + Z1_OFF;
  float* x4 = wsf + X4_OFF;
  int* idx  = (int*)(wsf + IDX_OFF);
  float* z2 = wsf + Z2_OFF;
  float* z3 = wsf + Z3_OFF;
  float* acc = wsf + ACC_OFF;
  float* xm = wsf + XM_OFF;
  float* biasF = wsf + BF_OFF;
  float* biasD = wsf + BD_OFF;
  float* d1 = wsf + X3_OFF;   // dead region before x3 written
  float* d2 = wsf + X4_OFF;   // dead region before x4 written
  float* dext = wsf + DEXT_OFF;
  const bool ext = ws_size >= EXT_NEED;

  const float inv_sites = 1.f / (float)(Bb * Nn);
  const int GP = Bb * Nn / 2 / 256;  // 64 x-blocks for site-pair kernels

  zero_acc<<<1, 1024, 0, stream>>>(acc);
  knn_kernel<<<dim3(Nn / 256, Bb, SEG), 256, 0, stream>>>(pts, knnp0);
  merge8<<<Bb * Nn / 256, 256, 0, stream>>>(knnp0, idx);

  s1_stats<<<Bb * Nn * 5 / 256, 256, 0, stream>>>(pts, idx, wposf, acc + 0);
  s1_apply<<<dim3(Bb * Nn / 256, 3), 256, 0, stream>>>(pts, idx, wposf, wposd, acc + 0, x1);

  // layer <21,21> LLR: fused p+d stats (scalar; small CIN), elementwise LLR (float4)
  vn_stats_pd<21, 21, 7, false><<<dim3(Bb * Nn / 256, 3), 256, 0, stream>>>(
      x1, w1f, w1d, 21, nullptr, nullptr, acc + 64, x2, d1);
  vn_llr_ew4<21><<<Bb * 21 * Nn / 4 / 256, 256, 0, stream>>>(acc + 64, inv_sites, x2, d1);

  // layer <21,42> LLR (scalar stats)
  vn_stats_pd<21, 42, 7, false><<<dim3(Bb * Nn / 256, 6), 256, 0, stream>>>(
      x2, w2f, w2d, 42, nullptr, nullptr, acc + 128, x3, d2);
  vn_llr_ew4<42><<<Bb * 42 * Nn / 4 / 256, 256, 0, stream>>>(acc + 128, inv_sites, x3, d2);

  // layer <42,85> no LLR: float2 p-only stats (OT=5, grid 64x17=1088) + elementwise BN
  vn_stats_pc2<42, 85, 5, false><<<dim3(GP, 17), 256, 0, stream>>>(
      x3, w3, 42, nullptr, acc + 256, x4);
  vn_bn4<85><<<Bb * 85 * Nn / 4 / 256, 256, 0, stream>>>(acc + 256, inv_sites, x4);

  s5_mean<<<Bb * 255, 256, 0, stream>>>(x4, xm, out);
  s5_bias<<<4, 256, 0, stream>>>(xm, ws1f, ws1d, biasF, biasD, out);

  if (ext) {
    // layer <85,85> LLR: float2 p+d stats (OT=5, grid 64x17=1088)
    vn_stats_pd2<85, 85, 5, true><<<dim3(GP, 17), 256, 0, stream>>>(
        x4, ws1f, ws1d, 170, biasF, biasD, acc + 512, z1, dext);
    vn_llr_ew4<85><<<Bb * 85 * Nn / 4 / 256, 256, 0, stream>>>(acc + 512, inv_sites, z1, dext);
    // layer <85,42> LLR: float2 p+d stats (OT=7, grid 64x6=384)
    vn_stats_pd2<85, 42, 7, false><<<dim3(GP, 6), 256, 0, stream>>>(
        z1, ws2f, ws2d, 85, nullptr, nullptr, acc + 768, z2, dext);
    vn_llr_ew4<42><<<Bb * 42 * Nn / 4 / 256, 256, 0, stream>>>(acc + 768, inv_sites, z2, dext);
  } else {
    vn_stats_pc<85, 85, 17, true><<<dim3(Bb * Nn / 256, 5), 256, 0, stream>>>(
        x4, ws1f, 170, biasF, acc + 512, z1);
    vn_apply_pc<85, 85, 17, true><<<dim3(Bb * Nn / 256, 5), 256, 0, stream>>>(
        x4, ws1d, 170, biasD, acc + 512, inv_sites, z1);
    vn_stats_pc<85, 42, 14, false><<<dim3(Bb * Nn / 256, 3), 256, 0, stream>>>(
        z1, ws2f, 85, nullptr, acc + 768, z2);
    vn_apply_pc<85, 42, 14, false><<<dim3(Bb * Nn / 256, 3), 256, 0, stream>>>(
        z1, ws2d, 85, nullptr, acc + 768, inv_sites, z2);
  }

  s8_z3<<<Bb * Nn / 256, 256, 0, stream>>>(z2, wlin, z3);
  s9_max<<<dim3(34, Bb), 256, 0, stream>>>(x4, xm, z3, out);
}

// Round 16
// 644.156 us; speedup vs baseline: 1.0936x; 1.0055x over previous
//
#include <hip/hip_runtime.h>
#include <cstdint>
#include <cstddef>

#define EPSF 1e-6f
#define BN_EPSF 1e-5f

constexpr int Bb = 4;
constexpr int Nn = 8192;
constexpr int KK = 20;
constexpr int SEG = 8;            // knn candidate segments
constexpr int SEGLEN = Nn / SEG;  // 1024
constexpr int BUF = 24;           // per-lane candidate buffer (LDS slots)

// ---------------- workspace layout (float elements) ----------------
constexpr size_t KNN0_OFF = 0;              // B*8*N*20 u32 = 5,242,880
constexpr size_t X1_OFF  = 0;               // B*21*3*N = 2,064,384
constexpr size_t X2_OFF  = 2064384;
constexpr size_t X3_OFF  = 4128768;         // B*42*3*N = 4,128,768 (ends 8,257,536)
constexpr size_t Z1_OFF  = 0;               // B*85*3*N = 8,355,840
constexpr size_t X4_OFF  = 8355840;         // 8,355,840
constexpr size_t IDX_OFF = 16711680;        // B*N*K ints = 655,360
constexpr size_t Z2_OFF  = 17367040;        // 4,128,768
constexpr size_t Z3_OFF  = 21495808;        // B*3*3*N = 294,912
constexpr size_t ACC_OFF = 21790720;        // 1024
constexpr size_t XM_OFF  = 21791744;        // 1020
constexpr size_t BF_OFF  = 21792764;        // 1020
constexpr size_t BD_OFF  = 21793784;        // 1020
constexpr size_t DEXT_OFF = 21795840;       // 8,355,840 (only if ws_size permits)
constexpr size_t EXT_NEED = (DEXT_OFF + 8355840) * 4;  // bytes

__device__ __forceinline__ float wave_sum(float v) {
#pragma unroll
  for (int off = 32; off; off >>= 1) v += __shfl_xor(v, off, 64);
  return v;
}
__device__ __forceinline__ float wave_max(float v) {
#pragma unroll
  for (int off = 32; off; off >>= 1) v = fmaxf(v, __shfl_xor(v, off, 64));
  return v;
}
__device__ __forceinline__ uint32_t umin32(uint32_t a, uint32_t b) { return a < b ? a : b; }
__device__ __forceinline__ uint32_t umax32(uint32_t a, uint32_t b) { return a < b ? b : a; }

// ---------------- KNN: buffered top-20, h-folded float screen ----------------
__global__ __launch_bounds__(256) void knn_kernel(const float* __restrict__ pts,
                                                  uint32_t* __restrict__ knnp) {
  __shared__ float4 tile[SEGLEN];          // 16 KB (xyz + 0.5|c|^2)
  __shared__ uint32_t buf[BUF * 256];      // 24 KB
  const int tid = threadIdx.x;
  const int n = blockIdx.x * 256 + tid;
  const int b = blockIdx.y;
  const int s = blockIdx.z;
  const float* pb = pts + (size_t)b * Nn * 3;

  for (int i = tid; i < SEGLEN; i += 256) {
    const float* p = pb + (size_t)(s * SEGLEN + i) * 3;
    const float x = p[0], y = p[1], z = p[2];
    tile[i] = make_float4(x, y, z, 0.5f * (x * x + y * y + z * z));
  }
  const float qx = pb[n * 3 + 0], qy = pb[n * 3 + 1], qz = pb[n * 3 + 2];
  const float nqx = -qx, nqy = -qy, nqz = -qz;
  const float h = 0.5f * (qx * qx + qy * qy + qz * qz);
  __syncthreads();

  uint32_t keys[KK];
#pragma unroll
  for (int j = 0; j < KK; ++j) keys[j] = 0xFFFFFFFFu;

  const int base = s * SEGLEN;

  // warmup: 40 candidates full-insert (enough to seed a tight threshold)
#pragma unroll 4
  for (int j = 0; j < 40; ++j) {
    const float4 c = tile[j];
    float u = fmaf(nqx, c.x, fmaf(nqy, c.y, fmaf(nqz, c.z, c.w + h)));
    u = fmaxf(u, 0.f);
    uint32_t mx = (__float_as_uint(u) & 0xFFFFE000u) | (uint32_t)(base + j);
#pragma unroll
    for (int q = 0; q < KK; ++q) {
      const uint32_t mn = umin32(keys[q], mx);
      mx = umax32(keys[q], mx);
      keys[q] = mn;
    }
  }

  uint32_t thresh = keys[KK - 1];
  float thresh_up = __uint_as_float((thresh & 0xFFFFE000u) + 0x2000u);
  float th_h = thresh_up - h + 2.4e-7f * fabsf(thresh_up) + 1e-30f;
  int cnt = 0;

  for (int j0 = 40; j0 < SEGLEN; j0 += 4) {
#pragma unroll
    for (int u4 = 0; u4 < 4; ++u4) {
      const int j = j0 + u4;
      const float4 c = tile[j];
      const float up = fmaf(nqx, c.x, fmaf(nqy, c.y, fmaf(nqz, c.z, c.w)));
      if (up < th_h) {
        const float uc = fmaxf(up + h, 0.f);
        buf[cnt * 256 + tid] = (__float_as_uint(uc) & 0xFFFFE000u) | (uint32_t)(base + j);
        ++cnt;
      }
    }
    if (__any(cnt > BUF - 4)) {
#pragma unroll
      for (int i = 0; i < BUF; ++i) {
        uint32_t mx = (i < cnt) ? buf[i * 256 + tid] : 0xFFFFFFFFu;
#pragma unroll
        for (int q = 0; q < KK; ++q) {
          const uint32_t mn = umin32(keys[q], mx);
          mx = umax32(keys[q], mx);
          keys[q] = mn;
        }
      }
      cnt = 0;
      thresh = keys[KK - 1];
      thresh_up = __uint_as_float((thresh & 0xFFFFE000u) + 0x2000u);
      th_h = thresh_up - h + 2.4e-7f * fabsf(thresh_up) + 1e-30f;
    }
  }
#pragma unroll
  for (int i = 0; i < BUF; ++i) {
    uint32_t mx = (i < cnt) ? buf[i * 256 + tid] : 0xFFFFFFFFu;
#pragma unroll
    for (int q = 0; q < KK; ++q) {
      const uint32_t mn = umin32(keys[q], mx);
      mx = umax32(keys[q], mx);
      keys[q] = mn;
    }
  }

  uint32_t* op = knnp + ((size_t)(b * SEG + s) * KK) * Nn + n;
#pragma unroll
  for (int j = 0; j < KK; ++j) op[(size_t)j * Nn] = keys[j];
}

// ---------------- single-pass 8-way merge (also zeroes acc via block 0) ----------------
__global__ __launch_bounds__(256) void merge8(const uint32_t* __restrict__ in,
                                              int* __restrict__ idx,
                                              float* __restrict__ accz) {
  if (blockIdx.x == 0) {
    for (int i = threadIdx.x; i < 1024; i += 256) accz[i] = 0.f;
  }
  const int t = blockIdx.x * 256 + threadIdx.x;  // B*N threads
  const int n = t & (Nn - 1), b = t >> 13;
  const uint32_t* base = in + ((size_t)(b * SEG) * KK) * Nn + n;
  uint32_t h[SEG];
  int ii[SEG];
#pragma unroll
  for (int s = 0; s < SEG; ++s) {
    h[s] = base[(size_t)s * KK * Nn];
    ii[s] = 1;
  }
  int* op = idx + (size_t)t * KK;
#pragma unroll
  for (int m = 0; m < KK; ++m) {
    uint32_t k = h[0];
#pragma unroll
    for (int s = 1; s < SEG; ++s) k = umin32(k, h[s]);
    op[m] = (int)(k & 8191u);
#pragma unroll
    for (int s = 0; s < SEG; ++s) {
      if (h[s] == k) {
        h[s] = (ii[s] < KK) ? base[(size_t)s * KK * Nn + (size_t)ii[s] * Nn] : 0xFFFFFFFFu;
        ii[s]++;
      }
    }
  }
}

// ---------------- stage 1: feature-cross + LLR(21) ----------------
__global__ __launch_bounds__(256) void s1_stats(const float* __restrict__ pts,
                                                const int* __restrict__ idx,
                                                const float* __restrict__ wf,
                                                float* __restrict__ acc) {
  __shared__ float lacc[42];
  const int tid = threadIdx.x;
  for (int i = tid; i < 42; i += 256) lacc[i] = 0.f;
  __syncthreads();
  const int t = blockIdx.x * 256 + tid;  // 0..B*N*5-1
  const int site = t / 5;
  const int kq = (t % 5) * 4;
  const int n = site & (Nn - 1), b = site >> 13;
  const float* pb = pts + (size_t)b * Nn * 3;
  const float cx = pb[n * 3 + 0], cy = pb[n * 3 + 1], cz = pb[n * 3 + 2];
  float s1a[21], s2a[21];
#pragma unroll
  for (int o = 0; o < 21; ++o) { s1a[o] = 0.f; s2a[o] = 0.f; }
#pragma unroll
  for (int k = kq; k < kq + 4; ++k) {
    const int m = idx[(size_t)site * KK + k];
    const float ax = pb[m * 3 + 0], ay = pb[m * 3 + 1], az = pb[m * 3 + 2];
    const float e0x = ax - cx, e0y = ay - cy, e0z = az - cz;
    const float e2x = ay * cz - az * cy, e2y = az * cx - ax * cz, e2z = ax * cy - ay * cx;
#pragma unroll
    for (int o = 0; o < 21; ++o) {
      const float w0 = wf[o * 3 + 0], w1 = wf[o * 3 + 1], w2 = wf[o * 3 + 2];
      const float px = w0 * e0x + w1 * cx + w2 * e2x;
      const float py = w0 * e0y + w1 * cy + w2 * e2y;
      const float pz = w0 * e0z + w1 * cz + w2 * e2z;
      const float nrm = sqrtf(px * px + py * py + pz * pz) + EPSF;
      s1a[o] += nrm;
      s2a[o] += nrm * nrm;
    }
  }
#pragma unroll
  for (int o = 0; o < 21; ++o) {
    const float s1 = wave_sum(s1a[o]);
    const float s2 = wave_sum(s2a[o]);
    if ((tid & 63) == 0) { atomicAdd(&lacc[o], s1); atomicAdd(&lacc[21 + o], s2); }
  }
  __syncthreads();
  for (int i = tid; i < 42; i += 256) atomicAdd(&acc[i], lacc[i]);
}

// tile of 7 output channels per block (blockIdx.y)
__global__ __launch_bounds__(256) void s1_apply(const float* __restrict__ pts,
                                                const int* __restrict__ idx,
                                                const float* __restrict__ wf,
                                                const float* __restrict__ wd,
                                                const float* __restrict__ acc,
                                                float* __restrict__ x1) {
  const int t = blockIdx.x * 256 + threadIdx.x;  // site 0..B*N-1
  const int o0 = blockIdx.y * 7;
  const int n = t & (Nn - 1), b = t >> 13;
  const float* pb = pts + (size_t)b * Nn * 3;
  const float cx = pb[n * 3 + 0], cy = pb[n * 3 + 1], cz = pb[n * 3 + 2];
  const float inv_cnt = 1.f / (float)(Bb * Nn * KK);
  float meano[7], istdo[7];
#pragma unroll
  for (int j = 0; j < 7; ++j) {
    const float mn = acc[o0 + j] * inv_cnt;
    const float vr = acc[21 + o0 + j] * inv_cnt - mn * mn;
    meano[j] = mn;
    istdo[j] = rsqrtf(vr + BN_EPSF);
  }
  float accu[7][3];
#pragma unroll
  for (int j = 0; j < 7; ++j) { accu[j][0] = 0.f; accu[j][1] = 0.f; accu[j][2] = 0.f; }
  for (int k = 0; k < KK; ++k) {
    const int m = idx[(size_t)t * KK + k];
    const float ax = pb[m * 3 + 0], ay = pb[m * 3 + 1], az = pb[m * 3 + 2];
    const float e0x = ax - cx, e0y = ay - cy, e0z = az - cz;
    const float e2x = ay * cz - az * cy, e2y = az * cx - ax * cz, e2z = ax * cy - ay * cx;
#pragma unroll
    for (int j = 0; j < 7; ++j) {
      const int o = o0 + j;
      const float wf0 = wf[o * 3 + 0], wf1 = wf[o * 3 + 1], wf2 = wf[o * 3 + 2];
      const float px = wf0 * e0x + wf1 * cx + wf2 * e2x;
      const float py = wf0 * e0y + wf1 * cy + wf2 * e2y;
      const float pz = wf0 * e0z + wf1 * cz + wf2 * e2z;
      const float nrm = sqrtf(px * px + py * py + pz * pz) + EPSF;
      const float factor = (nrm - meano[j]) * istdo[j] / nrm;
      const float q0 = px * factor, q1 = py * factor, q2 = pz * factor;
      const float wd0 = wd[o * 3 + 0], wd1 = wd[o * 3 + 1], wd2 = wd[o * 3 + 2];
      const float dx = wd0 * e0x + wd1 * cx + wd2 * e2x;
      const float dy = wd0 * e0y + wd1 * cy + wd2 * e2y;
      const float dz = wd0 * e0z + wd1 * cz + wd2 * e2z;
      const float dot = q0 * dx + q1 * dy + q2 * dz;
      const float dsq = dx * dx + dy * dy + dz * dz;
      const float corr = (dot < 0.f) ? dot / (dsq + EPSF) : 0.f;
      accu[j][0] += q0 - corr * dx;
      accu[j][1] += q1 - corr * dy;
      accu[j][2] += q2 - corr * dz;
    }
  }
  const float sc = 1.f / (float)KK;
  float* ob = x1 + (size_t)b * 21 * 3 * Nn + n;
#pragma unroll
  for (int j = 0; j < 7; ++j) {
    const int o = o0 + j;
    ob[(o * 3 + 0) * Nn] = accu[j][0] * sc;
    ob[(o * 3 + 1) * Nn] = accu[j][1] * sc;
    ob[(o * 3 + 2) * Nn] = accu[j][2] * sc;
  }
}

// ---------------- VN layer (scalar): stats computes p AND d ----------------
template <int CIN, int COUT, int OT, bool HAS_BIAS>
__global__ __launch_bounds__(256) void vn_stats_pd(const float* __restrict__ X,
                                                   const float* __restrict__ Wf,
                                                   const float* __restrict__ Wd, int ws,
                                                   const float* __restrict__ biasF,
                                                   const float* __restrict__ biasD,
                                                   float* __restrict__ acc,
                                                   float* __restrict__ P,
                                                   float* __restrict__ D) {
  __shared__ float lacc[2 * OT];
  const int tid = threadIdx.x;
  if (tid < 2 * OT) lacc[tid] = 0.f;
  __syncthreads();
  const int o0 = blockIdx.y * OT;
  const int t = blockIdx.x * 256 + tid;
  const int n = t & (Nn - 1), b = t >> 13;
  const float* xb = X + (size_t)b * CIN * 3 * Nn + n;
  float* pb = P + (size_t)b * COUT * 3 * Nn + n;
  float* db = D + (size_t)b * COUT * 3 * Nn + n;
  float p[OT][3], dv[OT][3];
#pragma unroll
  for (int j = 0; j < OT; ++j)
#pragma unroll
    for (int dd = 0; dd < 3; ++dd) {
      p[j][dd] = HAS_BIAS ? biasF[((size_t)b * COUT + o0 + j) * 3 + dd] : 0.f;
      dv[j][dd] = HAS_BIAS ? biasD[((size_t)b * COUT + o0 + j) * 3 + dd] : 0.f;
    }
  for (int c = 0; c < CIN; ++c) {
    const float x0 = xb[(c * 3 + 0) * Nn];
    const float x1v = xb[(c * 3 + 1) * Nn];
    const float x2v = xb[(c * 3 + 2) * Nn];
#pragma unroll
    for (int j = 0; j < OT; ++j) {
      const float wfv = Wf[(o0 + j) * ws + c];
      p[j][0] += wfv * x0; p[j][1] += wfv * x1v; p[j][2] += wfv * x2v;
      const float wdv = Wd[(o0 + j) * ws + c];
      dv[j][0] += wdv * x0; dv[j][1] += wdv * x1v; dv[j][2] += wdv * x2v;
    }
  }
#pragma unroll
  for (int j = 0; j < OT; ++j) {
    const int o = o0 + j;
    pb[(size_t)(o * 3 + 0) * Nn] = p[j][0];
    pb[(size_t)(o * 3 + 1) * Nn] = p[j][1];
    pb[(size_t)(o * 3 + 2) * Nn] = p[j][2];
    db[(size_t)(o * 3 + 0) * Nn] = dv[j][0];
    db[(size_t)(o * 3 + 1) * Nn] = dv[j][1];
    db[(size_t)(o * 3 + 2) * Nn] = dv[j][2];
  }
#pragma unroll
  for (int j = 0; j < OT; ++j) {
    const float nrm = sqrtf(p[j][0] * p[j][0] + p[j][1] * p[j][1] + p[j][2] * p[j][2]) + EPSF;
    const float s1 = wave_sum(nrm);
    const float s2 = wave_sum(nrm * nrm);
    if ((tid & 63) == 0) { atomicAdd(&lacc[j], s1); atomicAdd(&lacc[OT + j], s2); }
  }
  __syncthreads();
  if (tid < 2 * OT) {
    const int g = (tid < OT) ? (o0 + tid) : (COUT + o0 + (tid - OT));
    atomicAdd(&acc[g], lacc[tid]);
  }
}

// ---------------- VN layer (float2 across n): stats computes p AND d ----------------
template <int CIN, int COUT, int OT, bool HAS_BIAS>
__global__ __launch_bounds__(256) void vn_stats_pd2(const float* __restrict__ X,
                                                    const float* __restrict__ Wf,
                                                    const float* __restrict__ Wd, int ws,
                                                    const float* __restrict__ biasF,
                                                    const float* __restrict__ biasD,
                                                    float* __restrict__ acc,
                                                    float* __restrict__ P,
                                                    float* __restrict__ D) {
  __shared__ float lacc[2 * OT];
  const int tid = threadIdx.x;
  if (tid < 2 * OT) lacc[tid] = 0.f;
  __syncthreads();
  const int o0 = blockIdx.y * OT;
  const int sp = blockIdx.x * 256 + tid;        // site-pair
  const int n = (sp & (Nn / 2 - 1)) * 2, b = sp >> 12;
  const float* xb = X + (size_t)b * CIN * 3 * Nn + n;
  float* pb = P + (size_t)b * COUT * 3 * Nn + n;
  float* db = D + (size_t)b * COUT * 3 * Nn + n;
  float2 p[OT][3], dv[OT][3];
#pragma unroll
  for (int j = 0; j < OT; ++j)
#pragma unroll
    for (int dd = 0; dd < 3; ++dd) {
      const float bf = HAS_BIAS ? biasF[((size_t)b * COUT + o0 + j) * 3 + dd] : 0.f;
      const float bd = HAS_BIAS ? biasD[((size_t)b * COUT + o0 + j) * 3 + dd] : 0.f;
      p[j][dd] = make_float2(bf, bf);
      dv[j][dd] = make_float2(bd, bd);
    }
  for (int c = 0; c < CIN; ++c) {
    const float2 x0 = *(const float2*)(xb + (size_t)(c * 3 + 0) * Nn);
    const float2 x1v = *(const float2*)(xb + (size_t)(c * 3 + 1) * Nn);
    const float2 x2v = *(const float2*)(xb + (size_t)(c * 3 + 2) * Nn);
#pragma unroll
    for (int j = 0; j < OT; ++j) {
      const float wfv = Wf[(o0 + j) * ws + c];
      p[j][0].x += wfv * x0.x;  p[j][0].y += wfv * x0.y;
      p[j][1].x += wfv * x1v.x; p[j][1].y += wfv * x1v.y;
      p[j][2].x += wfv * x2v.x; p[j][2].y += wfv * x2v.y;
      const float wdv = Wd[(o0 + j) * ws + c];
      dv[j][0].x += wdv * x0.x;  dv[j][0].y += wdv * x0.y;
      dv[j][1].x += wdv * x1v.x; dv[j][1].y += wdv * x1v.y;
      dv[j][2].x += wdv * x2v.x; dv[j][2].y += wdv * x2v.y;
    }
  }
#pragma unroll
  for (int j = 0; j < OT; ++j) {
    const int o = o0 + j;
    *(float2*)(pb + (size_t)(o * 3 + 0) * Nn) = p[j][0];
    *(float2*)(pb + (size_t)(o * 3 + 1) * Nn) = p[j][1];
    *(float2*)(pb + (size_t)(o * 3 + 2) * Nn) = p[j][2];
    *(float2*)(db + (size_t)(o * 3 + 0) * Nn) = dv[j][0];
    *(float2*)(db + (size_t)(o * 3 + 1) * Nn) = dv[j][1];
    *(float2*)(db + (size_t)(o * 3 + 2) * Nn) = dv[j][2];
  }
#pragma unroll
  for (int j = 0; j < OT; ++j) {
    const float n0 = sqrtf(p[j][0].x * p[j][0].x + p[j][1].x * p[j][1].x + p[j][2].x * p[j][2].x) + EPSF;
    const float n1 = sqrtf(p[j][0].y * p[j][0].y + p[j][1].y * p[j][1].y + p[j][2].y * p[j][2].y) + EPSF;
    const float s1 = wave_sum(n0 + n1);
    const float s2 = wave_sum(n0 * n0 + n1 * n1);
    if ((tid & 63) == 0) { atomicAdd(&lacc[j], s1); atomicAdd(&lacc[OT + j], s2); }
  }
  __syncthreads();
  if (tid < 2 * OT) {
    const int g = (tid < OT) ? (o0 + tid) : (COUT + o0 + (tid - OT));
    atomicAdd(&acc[g], lacc[tid]);
  }
}

__device__ __forceinline__ float llr_one(float p0, float p1, float p2,
                                         float d0, float d1, float d2,
                                         float mn, float istd,
                                         float& r0o, float& r1o, float& r2o) {
  const float nrm = sqrtf(p0 * p0 + p1 * p1 + p2 * p2) + EPSF;
  const float factor = (nrm - mn) * istd / nrm;
  float r0 = p0 * factor, r1 = p1 * factor, r2 = p2 * factor;
  const float dot = r0 * d0 + r1 * d1 + r2 * d2;
  const float dsq = d0 * d0 + d1 * d1 + d2 * d2;
  const float corr = (dot < 0.f) ? dot / (dsq + EPSF) : 0.f;
  r0o = r0 - corr * d0; r1o = r1 - corr * d1; r2o = r2 - corr * d2;
  return 0.f;
}

// elementwise BN + LLR over cached p,d (float4 across n); writes P in place.
template <int COUT>
__global__ __launch_bounds__(256) void vn_llr_ew4(const float* __restrict__ acc, float cntinv,
                                                  float* __restrict__ P,
                                                  const float* __restrict__ D) {
  const int t = blockIdx.x * 256 + threadIdx.x;  // (b, o, n4)
  const int n4 = t & (Nn / 4 - 1);
  const int r = t >> 11;
  const int o = r % COUT, b = r / COUT;
  float4* pp = (float4*)(P + ((size_t)(b * COUT + o) * 3) * Nn) + n4;
  const float4* dp = (const float4*)(D + ((size_t)(b * COUT + o) * 3) * Nn) + n4;
  const float4 p0 = pp[0], p1 = pp[Nn / 4], p2 = pp[2 * (Nn / 4)];
  const float4 d0 = dp[0], d1 = dp[Nn / 4], d2 = dp[2 * (Nn / 4)];
  const float mn = acc[o] * cntinv;
  const float vr = acc[COUT + o] * cntinv - mn * mn;
  const float istd = rsqrtf(vr + BN_EPSF);
  float4 r0, r1, r2;
  llr_one(p0.x, p1.x, p2.x, d0.x, d1.x, d2.x, mn, istd, r0.x, r1.x, r2.x);
  llr_one(p0.y, p1.y, p2.y, d0.y, d1.y, d2.y, mn, istd, r0.y, r1.y, r2.y);
  llr_one(p0.z, p1.z, p2.z, d0.z, d1.z, d2.z, mn, istd, r0.z, r1.z, r2.z);
  llr_one(p0.w, p1.w, p2.w, d0.w, d1.w, d2.w, mn, istd, r0.w, r1.w, r2.w);
  pp[0] = r0;
  pp[Nn / 4] = r1;
  pp[2 * (Nn / 4)] = r2;
}

// ---------------- p-only stats: scalar + float2 variants ----------------
template <int CIN, int COUT, int OT, bool HAS_BIAS>
__global__ __launch_bounds__(256) void vn_stats_pc(const float* __restrict__ X,
                                                   const float* __restrict__ Wf, int ws,
                                                   const float* __restrict__ biasF,
                                                   float* __restrict__ acc,
                                                   float* __restrict__ P) {
  __shared__ float lacc[2 * OT];
  const int tid = threadIdx.x;
  if (tid < 2 * OT) lacc[tid] = 0.f;
  __syncthreads();
  const int o0 = blockIdx.y * OT;
  const int t = blockIdx.x * 256 + tid;
  const int n = t & (Nn - 1), b = t >> 13;
  const float* xb = X + (size_t)b * CIN * 3 * Nn + n;
  float* pb = P + (size_t)b * COUT * 3 * Nn + n;
  float p[OT][3];
#pragma unroll
  for (int j = 0; j < OT; ++j)
#pragma unroll
    for (int dd = 0; dd < 3; ++dd)
      p[j][dd] = HAS_BIAS ? biasF[((size_t)b * COUT + o0 + j) * 3 + dd] : 0.f;
  for (int c = 0; c < CIN; ++c) {
    const float x0 = xb[(c * 3 + 0) * Nn];
    const float x1v = xb[(c * 3 + 1) * Nn];
    const float x2v = xb[(c * 3 + 2) * Nn];
#pragma unroll
    for (int j = 0; j < OT; ++j) {
      const float wv = Wf[(o0 + j) * ws + c];
      p[j][0] += wv * x0; p[j][1] += wv * x1v; p[j][2] += wv * x2v;
    }
  }
#pragma unroll
  for (int j = 0; j < OT; ++j) {
    const int o = o0 + j;
    pb[(size_t)(o * 3 + 0) * Nn] = p[j][0];
    pb[(size_t)(o * 3 + 1) * Nn] = p[j][1];
    pb[(size_t)(o * 3 + 2) * Nn] = p[j][2];
  }
#pragma unroll
  for (int j = 0; j < OT; ++j) {
    const float nrm = sqrtf(p[j][0] * p[j][0] + p[j][1] * p[j][1] + p[j][2] * p[j][2]) + EPSF;
    const float s1 = wave_sum(nrm);
    const float s2 = wave_sum(nrm * nrm);
    if ((tid & 63) == 0) { atomicAdd(&lacc[j], s1); atomicAdd(&lacc[OT + j], s2); }
  }
  __syncthreads();
  if (tid < 2 * OT) {
    const int g = (tid < OT) ? (o0 + tid) : (COUT + o0 + (tid - OT));
    atomicAdd(&acc[g], lacc[tid]);
  }
}

template <int CIN, int COUT, int OT, bool HAS_BIAS>
__global__ __launch_bounds__(256) void vn_stats_pc2(const float* __restrict__ X,
                                                    const float* __restrict__ Wf, int ws,
                                                    const float* __restrict__ biasF,
                                                    float* __restrict__ acc,
                                                    float* __restrict__ P) {
  __shared__ float lacc[2 * OT];
  const int tid = threadIdx.x;
  if (tid < 2 * OT) lacc[tid] = 0.f;
  __syncthreads();
  const int o0 = blockIdx.y * OT;
  const int sp = blockIdx.x * 256 + tid;        // site-pair
  const int n = (sp & (Nn / 2 - 1)) * 2, b = sp >> 12;
  const float* xb = X + (size_t)b * CIN * 3 * Nn + n;
  float* pb = P + (size_t)b * COUT * 3 * Nn + n;
  float2 p[OT][3];
#pragma unroll
  for (int j = 0; j < OT; ++j)
#pragma unroll
    for (int dd = 0; dd < 3; ++dd) {
      const float bf = HAS_BIAS ? biasF[((size_t)b * COUT + o0 + j) * 3 + dd] : 0.f;
      p[j][dd] = make_float2(bf, bf);
    }
  for (int c = 0; c < CIN; ++c) {
    const float2 x0 = *(const float2*)(xb + (size_t)(c * 3 + 0) * Nn);
    const float2 x1v = *(const float2*)(xb + (size_t)(c * 3 + 1) * Nn);
    const float2 x2v = *(const float2*)(xb + (size_t)(c * 3 + 2) * Nn);
#pragma unroll
    for (int j = 0; j < OT; ++j) {
      const float wv = Wf[(o0 + j) * ws + c];
      p[j][0].x += wv * x0.x;  p[j][0].y += wv * x0.y;
      p[j][1].x += wv * x1v.x; p[j][1].y += wv * x1v.y;
      p[j][2].x += wv * x2v.x; p[j][2].y += wv * x2v.y;
    }
  }
#pragma unroll
  for (int j = 0; j < OT; ++j) {
    const int o = o0 + j;
    *(float2*)(pb + (size_t)(o * 3 + 0) * Nn) = p[j][0];
    *(float2*)(pb + (size_t)(o * 3 + 1) * Nn) = p[j][1];
    *(float2*)(pb + (size_t)(o * 3 + 2) * Nn) = p[j][2];
  }
#pragma unroll
  for (int j = 0; j < OT; ++j) {
    const float n0 = sqrtf(p[j][0].x * p[j][0].x + p[j][1].x * p[j][1].x + p[j][2].x * p[j][2].x) + EPSF;
    const float n1 = sqrtf(p[j][0].y * p[j][0].y + p[j][1].y * p[j][1].y + p[j][2].y * p[j][2].y) + EPSF;
    const float s1 = wave_sum(n0 + n1);
    const float s2 = wave_sum(n0 * n0 + n1 * n1);
    if ((tid & 63) == 0) { atomicAdd(&lacc[j], s1); atomicAdd(&lacc[OT + j], s2); }
  }
  __syncthreads();
  if (tid < 2 * OT) {
    const int g = (tid < OT) ? (o0 + tid) : (COUT + o0 + (tid - OT));
    atomicAdd(&acc[g], lacc[tid]);
  }
}

template <int CIN, int COUT, int OT, bool HAS_BIAS>
__global__ __launch_bounds__(256) void vn_apply_pc(const float* __restrict__ X,
                                                   const float* __restrict__ Wd, int ws,
                                                   const float* __restrict__ biasD,
                                                   const float* __restrict__ acc, float cntinv,
                                                   float* __restrict__ P) {
  const int o0 = blockIdx.y * OT;
  const int t = blockIdx.x * 256 + threadIdx.x;
  const int n = t & (Nn - 1), b = t >> 13;
  const float* xb = X + (size_t)b * CIN * 3 * Nn + n;
  float* pb = P + (size_t)b * COUT * 3 * Nn + n;
  float dv[OT][3];
#pragma unroll
  for (int j = 0; j < OT; ++j)
#pragma unroll
    for (int dd = 0; dd < 3; ++dd)
      dv[j][dd] = HAS_BIAS ? biasD[((size_t)b * COUT + o0 + j) * 3 + dd] : 0.f;
  for (int c = 0; c < CIN; ++c) {
    const float x0 = xb[(c * 3 + 0) * Nn];
    const float x1v = xb[(c * 3 + 1) * Nn];
    const float x2v = xb[(c * 3 + 2) * Nn];
#pragma unroll
    for (int j = 0; j < OT; ++j) {
      const float wdv = Wd[(o0 + j) * ws + c];
      dv[j][0] += wdv * x0; dv[j][1] += wdv * x1v; dv[j][2] += wdv * x2v;
    }
  }
#pragma unroll
  for (int j = 0; j < OT; ++j) {
    const int o = o0 + j;
    const float p0 = pb[(size_t)(o * 3 + 0) * Nn];
    const float p1 = pb[(size_t)(o * 3 + 1) * Nn];
    const float p2 = pb[(size_t)(o * 3 + 2) * Nn];
    const float nrm = sqrtf(p0 * p0 + p1 * p1 + p2 * p2) + EPSF;
    const float mn = acc[o] * cntinv;
    const float vr = acc[COUT + o] * cntinv - mn * mn;
    const float factor = (nrm - mn) * rsqrtf(vr + BN_EPSF) / nrm;
    float r0 = p0 * factor, r1 = p1 * factor, r2 = p2 * factor;
    const float dot = r0 * dv[j][0] + r1 * dv[j][1] + r2 * dv[j][2];
    const float dsq = dv[j][0] * dv[j][0] + dv[j][1] * dv[j][1] + dv[j][2] * dv[j][2];
    const float corr = (dot < 0.f) ? dot / (dsq + EPSF) : 0.f;
    r0 -= corr * dv[j][0]; r1 -= corr * dv[j][1]; r2 -= corr * dv[j][2];
    pb[(size_t)(o * 3 + 0) * Nn] = r0;
    pb[(size_t)(o * 3 + 1) * Nn] = r1;
    pb[(size_t)(o * 3 + 2) * Nn] = r2;
  }
}

// non-LLR layer fallback: elementwise BN over cached p (float4 across n), in place.
template <int COUT>
__global__ __launch_bounds__(256) void vn_bn4(const float* __restrict__ acc, float cntinv,
                                              float* __restrict__ P) {
  const int t = blockIdx.x * 256 + threadIdx.x;  // (b, o, n4)
  const int n4 = t & (Nn / 4 - 1);
  const int r = t >> 11;
  const int o = r % COUT, b = r / COUT;
  float4* pp = (float4*)(P + ((size_t)(b * COUT + o) * 3) * Nn) + n4;
  const float4 p0 = pp[0], p1 = pp[Nn / 4], p2 = pp[2 * (Nn / 4)];
  const float mn = acc[o] * cntinv;
  const float vr = acc[COUT + o] * cntinv - mn * mn;
  const float istd = rsqrtf(vr + BN_EPSF);
  float4 r0, r1, r2;
#define BN_ONE(f) {                                                        \
    const float nrm = sqrtf(p0.f * p0.f + p1.f * p1.f + p2.f * p2.f) + EPSF; \
    const float factor = (nrm - mn) * istd / nrm;                          \
    r0.f = p0.f * factor; r1.f = p1.f * factor; r2.f = p2.f * factor; }
  BN_ONE(x) BN_ONE(y) BN_ONE(z) BN_ONE(w)
#undef BN_ONE
  pp[0] = r0;
  pp[Nn / 4] = r1;
  pp[2 * (Nn / 4)] = r2;
}

// ---------------- fused layer-3 BN + mean over N + small outputs ----------------
// grid: B*85 blocks; each handles the 3 components of one (b,c); x4 normalized in place.
__global__ __launch_bounds__(256) void s5_bn_mean(const float* __restrict__ acc, float cntinv,
                                                  float* __restrict__ x4,
                                                  float* __restrict__ xm,
                                                  float* __restrict__ out) {
  const int bc = blockIdx.x;          // 0..339 = b*85+c
  const int b = bc / 85, c = bc % 85;
  const int tid = threadIdx.x;
  const float mn = acc[c] * cntinv;
  const float vr = acc[85 + c] * cntinv - mn * mn;
  const float istd = rsqrtf(vr + BN_EPSF);
  float* base = x4 + ((size_t)(b * 85 + c) * 3) * Nn;
  float s0 = 0.f, s1 = 0.f, s2 = 0.f;
  for (int n = tid; n < Nn; n += 256) {
    const float p0 = base[n], p1 = base[Nn + n], p2 = base[2 * Nn + n];
    const float nrm = sqrtf(p0 * p0 + p1 * p1 + p2 * p2) + EPSF;
    const float factor = (nrm - mn) * istd / nrm;
    const float r0 = p0 * factor, r1 = p1 * factor, r2 = p2 * factor;
    base[n] = r0; base[Nn + n] = r1; base[2 * Nn + n] = r2;
    s0 += r0; s1 += r1; s2 += r2;
  }
  s0 = wave_sum(s0); s1 = wave_sum(s1); s2 = wave_sum(s2);
  __shared__ float red[4][3];
  if ((tid & 63) == 0) { red[tid >> 6][0] = s0; red[tid >> 6][1] = s1; red[tid >> 6][2] = s2; }
  __syncthreads();
  if (tid < 3) {
    const float mv = (red[0][tid] + red[1][tid] + red[2][tid] + red[3][tid]) * (1.f / (float)Nn);
    const int row = bc * 3 + tid;  // == b*255 + c*3 + dd
    xm[row] = mv;
    out[2040 + row] = mv;  // x_mean_out
  }
}

__global__ __launch_bounds__(256) void s5_bias(const float* __restrict__ xm,
                                               const float* __restrict__ ws1f,
                                               const float* __restrict__ ws1d,
                                               float* __restrict__ biasF,
                                               float* __restrict__ biasD,
                                               float* __restrict__ out) {
  const int t = blockIdx.x * 256 + threadIdx.x;
  if (t < 1020) {
    const int b = t / 255, r = t % 255, o = r / 3, dd = r % 3;
    float sf = 0.f, sd = 0.f;
    for (int c = 0; c < 85; ++c) {
      const float xv = xm[(b * 85 + c) * 3 + dd];
      sf += ws1f[o * 170 + 85 + c] * xv;
      sd += ws1d[o * 170 + 85 + c] * xv;
    }
    biasF[t] = sf;
    biasD[t] = sd;
  }
  if (t < 340) {
    const int b = t / 85, c = t % 85;
    out[3060 + t] = (xm[(b * 85 + c) * 3 + 0] + xm[(b * 85 + c) * 3 + 1] +
                     xm[(b * 85 + c) * 3 + 2]) * (1.f / 3.f);  // center_loc
  }
}

// ---------------- stage 8: z3 = wlin · z2 ----------------
__global__ __launch_bounds__(256) void s8_z3(const float* __restrict__ z2,
                                             const float* __restrict__ wlin,
                                             float* __restrict__ z3) {
  const int t = blockIdx.x * 256 + threadIdx.x;
  const int n = t & (Nn - 1), b = t >> 13;
  const float* zb = z2 + (size_t)b * 42 * 3 * Nn + n;
  float accv[3][3];
#pragma unroll
  for (int o = 0; o < 3; ++o)
#pragma unroll
    for (int dd = 0; dd < 3; ++dd) accv[o][dd] = 0.f;
  for (int c = 0; c < 42; ++c) {
    const float x0 = zb[(c * 3 + 0) * Nn];
    const float x1v = zb[(c * 3 + 1) * Nn];
    const float x2v = zb[(c * 3 + 2) * Nn];
#pragma unroll
    for (int o = 0; o < 3; ++o) {
      const float wv = wlin[o * 42 + c];
      accv[o][0] += wv * x0; accv[o][1] += wv * x1v; accv[o][2] += wv * x2v;
    }
  }
  float* ob = z3 + (size_t)b * 9 * Nn + n;
#pragma unroll
  for (int o = 0; o < 3; ++o)
#pragma unroll
    for (int dd = 0; dd < 3; ++dd) ob[(o * 3 + dd) * Nn] = accv[o][dd];
}

// ---------------- stage 9: x_std + max over N ----------------
__global__ __launch_bounds__(256) void s9_max(const float* __restrict__ x4,
                                              const float* __restrict__ xm,
                                              const float* __restrict__ z3,
                                              float* __restrict__ out) {
  const int tile = blockIdx.x;  // 0..33
  const int b = blockIdx.y;
  const int i0 = tile * 5;
  const bool upper = (i0 >= 85);
  float mx[15];
#pragma unroll
  for (int r = 0; r < 15; ++r) mx[r] = -3.402823466e38f;
  float xmr[5][3];
  if (upper) {
#pragma unroll
    for (int ii = 0; ii < 5; ++ii)
#pragma unroll
      for (int j = 0; j < 3; ++j) xmr[ii][j] = xm[(b * 85 + (i0 - 85 + ii)) * 3 + j];
  }
  const float* zb = z3 + (size_t)b * 9 * Nn;
  const float* xb = x4 + (size_t)b * 255 * Nn;
  for (int n = threadIdx.x; n < Nn; n += 256) {
    float zk[3][3];
#pragma unroll
    for (int k = 0; k < 3; ++k)
#pragma unroll
      for (int j = 0; j < 3; ++j) zk[k][j] = zb[(k * 3 + j) * Nn + n];
#pragma unroll
    for (int ii = 0; ii < 5; ++ii) {
      float xj0, xj1, xj2;
      if (upper) {
        xj0 = xmr[ii][0]; xj1 = xmr[ii][1]; xj2 = xmr[ii][2];
      } else {
        xj0 = xb[((i0 + ii) * 3 + 0) * Nn + n];
        xj1 = xb[((i0 + ii) * 3 + 1) * Nn + n];
        xj2 = xb[((i0 + ii) * 3 + 2) * Nn + n];
      }
#pragma unroll
      for (int k = 0; k < 3; ++k) {
        const float v = xj0 * zk[k][0] + xj1 * zk[k][1] + xj2 * zk[k][2];
        mx[ii * 3 + k] = fmaxf(mx[ii * 3 + k], v);
      }
    }
  }
  __shared__ float red[4 * 15];
#pragma unroll
  for (int r = 0; r < 15; ++r) {
    const float v = wave_max(mx[r]);
    if ((threadIdx.x & 63) == 0) red[(threadIdx.x >> 6) * 15 + r] = v;
  }
  __syncthreads();
  if (threadIdx.x < 15) {
    const float v = fmaxf(fmaxf(red[threadIdx.x], red[15 + threadIdx.x]),
                          fmaxf(red[30 + threadIdx.x], red[45 + threadIdx.x]));
    out[b * 510 + i0 * 3 + threadIdx.x] = v;
  }
}

// ---------------- launch ----------------
extern "C" void kernel_launch(void* const* d_in, const int* in_sizes, int n_in,
                              void* d_out, int out_size, void* d_ws, size_t ws_size,
                              hipStream_t stream) {
  const float* pts   = (const float*)d_in[0];
  const float* wposf = (const float*)d_in[1];
  const float* wposd = (const float*)d_in[2];
  const float* w1f   = (const float*)d_in[3];
  const float* w1d   = (const float*)d_in[4];
  const float* w2f   = (const float*)d_in[5];
  const float* w2d   = (const float*)d_in[6];
  const float* w3    = (const float*)d_in[7];
  const float* ws1f  = (const float*)d_in[8];
  const float* ws1d  = (const float*)d_in[9];
  const float* ws2f  = (const float*)d_in[10];
  const float* ws2d  = (const float*)d_in[11];
  const float* wlin  = (const float*)d_in[12];
  float* out = (float*)d_out;
  float* wsf = (float*)d_ws;

  uint32_t* knnp0 = (uint32_t*)(wsf + KNN0_OFF);
  float* x1 = wsf + X1_OFF;
  float* x2 = wsf + X2_OFF;
  float* x3 = wsf + X3_OFF;
  float* z1 = wsf + Z1_OFF;
  float* x4 = wsf + X4_OFF;
  int* idx  = (int*)(wsf + IDX_OFF);
  float* z2 = wsf + Z2_OFF;
  float* z3 = wsf + Z3_OFF;
  float* acc = wsf + ACC_OFF;
  float* xm = wsf + XM_OFF;
  float* biasF = wsf + BF_OFF;
  float* biasD = wsf + BD_OFF;
  float* d1 = wsf + X3_OFF;   // dead region before x3 written
  float* d2 = wsf + X4_OFF;   // dead region before x4 written
  float* dext = wsf + DEXT_OFF;
  const bool ext = ws_size >= EXT_NEED;

  const float inv_sites = 1.f / (float)(Bb * Nn);
  const int GP = Bb * Nn / 2 / 256;  // 64 x-blocks for site-pair kernels

  knn_kernel<<<dim3(Nn / 256, Bb, SEG), 256, 0, stream>>>(pts, knnp0);
  merge8<<<Bb * Nn / 256, 256, 0, stream>>>(knnp0, idx, acc);  // also zeroes acc

  s1_stats<<<Bb * Nn * 5 / 256, 256, 0, stream>>>(pts, idx, wposf, acc + 0);
  s1_apply<<<dim3(Bb * Nn / 256, 3), 256, 0, stream>>>(pts, idx, wposf, wposd, acc + 0, x1);

  // layer <21,21> LLR: fused p+d stats (scalar; small CIN), elementwise LLR (float4)
  vn_stats_pd<21, 21, 7, false><<<dim3(Bb * Nn / 256, 3), 256, 0, stream>>>(
      x1, w1f, w1d, 21, nullptr, nullptr, acc + 64, x2, d1);
  vn_llr_ew4<21><<<Bb * 21 * Nn / 4 / 256, 256, 0, stream>>>(acc + 64, inv_sites, x2, d1);

  // layer <21,42> LLR (scalar stats)
  vn_stats_pd<21, 42, 7, false><<<dim3(Bb * Nn / 256, 6), 256, 0, stream>>>(
      x2, w2f, w2d, 42, nullptr, nullptr, acc + 128, x3, d2);
  vn_llr_ew4<42><<<Bb * 42 * Nn / 4 / 256, 256, 0, stream>>>(acc + 128, inv_sites, x3, d2);

  // layer <42,85> no LLR: float2 p-only stats (OT=5, grid 64x17=1088)
  vn_stats_pc2<42, 85, 5, false><<<dim3(GP, 17), 256, 0, stream>>>(
      x3, w3, 42, nullptr, acc + 256, x4);
  // fused BN + mean-over-N + x_mean_out write (saves one full x4 read + a dispatch)
  s5_bn_mean<<<Bb * 85, 256, 0, stream>>>(acc + 256, inv_sites, x4, xm, out);
  s5_bias<<<4, 256, 0, stream>>>(xm, ws1f, ws1d, biasF, biasD, out);

  if (ext) {
    // layer <85,85> LLR: float2 p+d stats (OT=5, grid 64x17=1088)
    vn_stats_pd2<85, 85, 5, true><<<dim3(GP, 17), 256, 0, stream>>>(
        x4, ws1f, ws1d, 170, biasF, biasD, acc + 512, z1, dext);
    vn_llr_ew4<85><<<Bb * 85 * Nn / 4 / 256, 256, 0, stream>>>(acc + 512, inv_sites, z1, dext);
    // layer <85,42> LLR: float2 p+d stats (OT=7, grid 64x6=384)
    vn_stats_pd2<85, 42, 7, false><<<dim3(GP, 6), 256, 0, stream>>>(
        z1, ws2f, ws2d, 85, nullptr, nullptr, acc + 768, z2, dext);
    vn_llr_ew4<42><<<Bb * 42 * Nn / 4 / 256, 256, 0, stream>>>(acc + 768, inv_sites, z2, dext);
  } else {
    vn_stats_pc<85, 85, 17, true><<<dim3(Bb * Nn / 256, 5), 256, 0, stream>>>(
        x4, ws1f, 170, biasF, acc + 512, z1);
    vn_apply_pc<85, 85, 17, true><<<dim3(Bb * Nn / 256, 5), 256, 0, stream>>>(
        x4, ws1d, 170, biasD, acc + 512, inv_sites, z1);
    vn_stats_pc<85, 42, 14, false><<<dim3(Bb * Nn / 256, 3), 256, 0, stream>>>(
        z1, ws2f, 85, nullptr, acc + 768, z2);
    vn_apply_pc<85, 42, 14, false><<<dim3(Bb * Nn / 256, 3), 256, 0, stream>>>(
        z1, ws2d, 85, nullptr, acc + 768, inv_sites, z2);
  }

  s8_z3<<<Bb * Nn / 256, 256, 0, stream>>>(z2, wlin, z3);
  s9_max<<<dim3(34, Bb), 256, 0, stream>>>(x4, xm, z3, out);
}